// Round 10
// baseline (79.068 us; speedup 1.0000x reference)
//
#include <hip/hip_runtime.h>
#include <hip/hip_bf16.h>

// Self-attention, fused QKV: x[4,2048,1024] f32, Wq/Wk/Wv[1024,64] f32 -> out[4,2048,64] f32
// bf16 MFMA (16x16x32), fp32 accumulation.
//   K1: W -> Wt bf16 [192][1024] via LDS tile-transpose (coalesced both sides)
//   K2: QKV projection, 512 blocks x 4 waves, M=16/block, FULL-K loop (no k-split),
//       waves split N 4-ways; deep unroll for load pipelining; V via LDS transpose.
//   K3: flash attention (round-7 proven): swapped operands (lane owns one query),
//       split-KV x8, no barriers in KV loop, deterministic combine.

typedef __attribute__((ext_vector_type(8))) short bf16x8;
typedef __attribute__((ext_vector_type(4))) float f32x4;
typedef __attribute__((ext_vector_type(4))) unsigned short u16x4;

#define QSCALE 0.1803368801111832f   // 0.125 * log2(e); makes logits exp2-domain

__device__ __forceinline__ short f2bf(float f) {
    union { float f; unsigned u; } v; v.f = f;
    unsigned r = v.u + 0x7FFF + ((v.u >> 16) & 1);   // round-to-nearest-even
    return (short)(r >> 16);
}

// ---------------- K1: weight transpose + bf16 convert (coalesced) ----------------
__global__ __launch_bounds__(256) void wtrans(const float* __restrict__ Wq,
                                              const float* __restrict__ Wk,
                                              const float* __restrict__ Wv,
                                              short* __restrict__ Wt) {
    __shared__ short lds[64][66];
    int warr = blockIdx.x / 16;
    int d0 = (blockIdx.x % 16) * 64;
    const float* W = (warr == 0) ? Wq : (warr == 1) ? Wk : Wv;
    int rg = threadIdx.x >> 6;
    int c  = threadIdx.x & 63;
    #pragma unroll
    for (int p = 0; p < 16; ++p) {
        int d = p * 4 + rg;
        lds[d][c] = f2bf(W[(d0 + d) * 64 + c]);
    }
    __syncthreads();
    #pragma unroll
    for (int p = 0; p < 16; ++p) {
        int n = p * 4 + rg;
        Wt[(warr * 64 + n) * 1024 + d0 + c] = lds[c][n];
    }
}

// ---------------- K2: QKV projection ----------------
// grid 512 blocks x 256 thr (4 waves). Block: M=16 rows, N=192, K=1024 (full).
// wave wid = wc: n-frags {wc, wc+4, wc+8} -> cols n / 64+n / 128+n with n = wc*16+l15.
// All 4 waves stream the SAME 16 x-rows (L1 reuse). acc = 12 VGPRs; the rest of the
// register file is load-pipeline depth (unroll 4).
__global__ __launch_bounds__(256) void qkv_proj(const float* __restrict__ x,
                                                const short* __restrict__ Wt,
                                                short* __restrict__ Q,
                                                short* __restrict__ K,
                                                short* __restrict__ Vt) {
    __shared__ short Vlds[16][72];
    int wid  = threadIdx.x >> 6;
    int lane = threadIdx.x & 63;
    int l15 = lane & 15, lg = lane >> 4;
    int mbase = blockIdx.x * 16;
    int row = mbase + l15;

    f32x4 acc0 = (f32x4){0.f, 0.f, 0.f, 0.f};
    f32x4 acc1 = acc0, acc2 = acc0;

    const float* xp0 = x + row * 1024 + lg * 8;
    const short* Wp0 = Wt + (wid * 16 + l15) * 1024 + lg * 8;
    const short* Wp1 = Wp0 + 64 * 1024;
    const short* Wp2 = Wp1 + 64 * 1024;

    #pragma unroll 4
    for (int d0 = 0; d0 < 1024; d0 += 32) {
        float4 x0 = *(const float4*)(xp0 + d0);
        float4 x1 = *(const float4*)(xp0 + d0 + 4);
        bf16x8 b0 = *(const bf16x8*)(Wp0 + d0);
        bf16x8 b1 = *(const bf16x8*)(Wp1 + d0);
        bf16x8 b2 = *(const bf16x8*)(Wp2 + d0);
        bf16x8 a;
        a[0] = f2bf(x0.x); a[1] = f2bf(x0.y); a[2] = f2bf(x0.z); a[3] = f2bf(x0.w);
        a[4] = f2bf(x1.x); a[5] = f2bf(x1.y); a[6] = f2bf(x1.z); a[7] = f2bf(x1.w);
        acc0 = __builtin_amdgcn_mfma_f32_16x16x32_bf16(a, b0, acc0, 0, 0, 0);
        acc1 = __builtin_amdgcn_mfma_f32_16x16x32_bf16(a, b1, acc1, 0, 0, 0);
        acc2 = __builtin_amdgcn_mfma_f32_16x16x32_bf16(a, b2, acc2, 0, 0, 0);
    }

    // epilogue: Q (scaled) and K direct (32B segments); V -> LDS transpose
    {
        int n = wid * 16 + l15;
        #pragma unroll
        for (int r = 0; r < 4; ++r) {
            int m = mbase + lg * 4 + r;
            Q[m * 64 + n] = f2bf(acc0[r] * QSCALE);
            K[m * 64 + n] = f2bf(acc1[r]);
            Vlds[lg * 4 + r][n] = f2bf(acc2[r]);
        }
    }
    __syncthreads();
    // Vt[(b*64+dk)*2048 + mbase + m]: 1024 elems, 256 thr, 4 each (8B coalesced-ish)
    {
        int t = threadIdx.x;
        int dk = t >> 2;              // 0..63
        int m0 = (t & 3) * 4;         // 0,4,8,12
        u16x4 v;
        #pragma unroll
        for (int i = 0; i < 4; ++i) v[i] = (unsigned short)Vlds[m0 + i][dk];
        int b_ = mbase >> 11;
        int s_ = mbase & 2047;
        *(u16x4*)&Vt[(b_ * 64 + dk) * 2048 + s_ + m0] = v;
    }
}

// ---------------- K3: flash attention (round-7), swapped operands, split-KV ----------------
// grid = 4*128 = 512 blocks, 512 thr (8 waves). Each wave: same 16 queries, 256-key slice.
__global__ __launch_bounds__(512) void attn(const short* __restrict__ Q,
                                            const short* __restrict__ K,
                                            const short* __restrict__ Vt,
                                            float* __restrict__ out) {
    __shared__ float accw[8][16][68];
    __shared__ short P_lds[8][16][72];
    __shared__ float Mw[8][16];
    __shared__ float Lw[8][16];
    __shared__ float Ltot[16];

    int tid = threadIdx.x, wid = tid >> 6, lane = tid & 63;
    int l15 = lane & 15, lg = lane >> 4;
    int b_ = blockIdx.x >> 7;
    int q0 = (blockIdx.x & 127) * 16;
    const short* Kb = K + b_ * 2048 * 64;
    const short* Vb = Vt + b_ * 64 * 2048;

    const short* Qp = Q + (b_ * 2048 + q0 + l15) * 64 + lg * 8;
    bf16x8 bq0 = *(const bf16x8*)Qp;
    bf16x8 bq1 = *(const bf16x8*)(Qp + 32);

    f32x4 acc[4];
    #pragma unroll
    for (int t = 0; t < 4; ++t) acc[t] = (f32x4){0.f, 0.f, 0.f, 0.f};
    float m_run = -INFINITY, l_run = 0.f;

    int kv0 = wid * 256;
    for (int kv = kv0; kv < kv0 + 256; kv += 64) {
        f32x4 s[4];
        #pragma unroll
        for (int kt = 0; kt < 4; ++kt) {
            const short* Kp = Kb + (kv + kt * 16 + l15) * 64 + lg * 8;
            bf16x8 ak0 = *(const bf16x8*)Kp;
            bf16x8 ak1 = *(const bf16x8*)(Kp + 32);
            f32x4 z = (f32x4){0.f, 0.f, 0.f, 0.f};
            z = __builtin_amdgcn_mfma_f32_16x16x32_bf16(ak0, bq0, z, 0, 0, 0);
            s[kt] = __builtin_amdgcn_mfma_f32_16x16x32_bf16(ak1, bq1, z, 0, 0, 0);
        }

        float m01 = fmaxf(fmaxf(s[0][0], s[0][1]), fmaxf(s[0][2], s[0][3]));
        float m23 = fmaxf(fmaxf(s[1][0], s[1][1]), fmaxf(s[1][2], s[1][3]));
        float m45 = fmaxf(fmaxf(s[2][0], s[2][1]), fmaxf(s[2][2], s[2][3]));
        float m67 = fmaxf(fmaxf(s[3][0], s[3][1]), fmaxf(s[3][2], s[3][3]));
        float mt = fmaxf(fmaxf(m01, m23), fmaxf(m45, m67));
        mt = fmaxf(mt, __shfl_xor(mt, 16));
        mt = fmaxf(mt, __shfl_xor(mt, 32));
        float mn = fmaxf(m_run, mt);
        float c = exp2f(m_run - mn);
        m_run = mn;
        float rs = 0.f;
        #pragma unroll
        for (int kt = 0; kt < 4; ++kt)
            #pragma unroll
            for (int r = 0; r < 4; ++r) {
                float p = exp2f(s[kt][r] - mn);
                s[kt][r] = p;
                rs += p;
            }
        rs += __shfl_xor(rs, 16);
        rs += __shfl_xor(rs, 32);
        l_run = l_run * c + rs;
        #pragma unroll
        for (int t = 0; t < 4; ++t)
            #pragma unroll
            for (int r = 0; r < 4; ++r) acc[t][r] *= c;

        #pragma unroll
        for (int kt = 0; kt < 4; ++kt) {
            u16x4 h;
            h[0] = (unsigned short)f2bf(s[kt][0]);
            h[1] = (unsigned short)f2bf(s[kt][1]);
            h[2] = (unsigned short)f2bf(s[kt][2]);
            h[3] = (unsigned short)f2bf(s[kt][3]);
            *(u16x4*)&P_lds[wid][l15][kt * 16 + lg * 4] = h;
        }

        #pragma unroll
        for (int ps = 0; ps < 2; ++ps) {
            bf16x8 bp = *(const bf16x8*)&P_lds[wid][l15][ps * 32 + lg * 8];
            #pragma unroll
            for (int t = 0; t < 4; ++t) {
                const short* Vp = Vb + (t * 16 + l15) * 2048 + kv + ps * 32 + lg * 8;
                bf16x8 av = *(const bf16x8*)Vp;
                acc[t] = __builtin_amdgcn_mfma_f32_16x16x32_bf16(av, bp, acc[t], 0, 0, 0);
            }
        }
    }

    if (lg == 0) {
        Mw[wid][l15] = m_run;
        Lw[wid][l15] = l_run;
    }
    __syncthreads();

    float mtot = Mw[0][l15];
    #pragma unroll
    for (int w = 1; w < 8; ++w) mtot = fmaxf(mtot, Mw[w][l15]);
    float fac = exp2f(m_run - mtot);
    #pragma unroll
    for (int t = 0; t < 4; ++t) {
        f32x4 v = acc[t];
        v[0] *= fac; v[1] *= fac; v[2] *= fac; v[3] *= fac;
        *(f32x4*)&accw[wid][l15][t * 16 + lg * 4] = v;
    }

    if (wid == 0 && lg == 0) {
        float L = 0.f;
        #pragma unroll
        for (int w = 0; w < 8; ++w)
            L += Lw[w][l15] * exp2f(Mw[w][l15] - mtot);
        Ltot[l15] = L;
    }
    __syncthreads();

    #pragma unroll
    for (int j = 0; j < 2; ++j) {
        int o = tid + j * 512;
        int row = o >> 6, col = o & 63;
        float ssum = 0.f;
        #pragma unroll
        for (int w = 0; w < 8; ++w) ssum += accw[w][row][col];
        out[(b_ * 2048 + q0 + row) * 64 + col] = ssum / Ltot[row];
    }
}

extern "C" void kernel_launch(void* const* d_in, const int* in_sizes, int n_in,
                              void* d_out, int out_size, void* d_ws, size_t ws_size,
                              hipStream_t stream) {
    const float* x  = (const float*)d_in[0];
    const float* Wq = (const float*)d_in[1];
    const float* Wk = (const float*)d_in[2];
    const float* Wv = (const float*)d_in[3];
    float* out = (float*)d_out;

    char* ws = (char*)d_ws;
    short* Wt = (short*)ws;                              // 192*1024*2   = 393216 B
    short* Q  = (short*)(ws + 393216);                   // 8192*64*2    = 1048576 B
    short* K  = (short*)(ws + 393216 + 1048576);         // 1048576 B
    short* Vt = (short*)(ws + 393216 + 2 * 1048576);     // 1048576 B   (total ~3.4 MB)

    hipLaunchKernelGGL(wtrans,   dim3(48),  dim3(256), 0, stream, Wq, Wk, Wv, Wt);
    hipLaunchKernelGGL(qkv_proj, dim3(512), dim3(256), 0, stream, x, Wt, Q, K, Vt);
    hipLaunchKernelGGL(attn,     dim3(512), dim3(512), 0, stream, Q, K, Vt, out);
}

// Round 11
// 78.818 us; speedup vs baseline: 1.0032x; 1.0032x over previous
//
#include <hip/hip_runtime.h>
#include <hip/hip_bf16.h>

// Self-attention, fused QKV: x[4,2048,1024] f32, Wq/Wk/Wv[1024,64] f32 -> out[4,2048,64] f32
// bf16 MFMA (16x16x32), fp32 accumulation.
//   K1: W -> Wt bf16 [192][1024] via LDS tile-transpose (coalesced both sides)
//   K2: QKV projection, 512 blocks x 4 waves, M=16/block, full K, PF=8 explicit
//       register software-pipeline (launch_bounds(256,2) frees the VGPR budget) —
//       hides ~600cy L3 latency that serialized rounds 2-10.
//   K3: flash attention (round-7 proven): swapped operands (lane owns one query),
//       split-KV x8, no barriers in KV loop, deterministic combine.

typedef __attribute__((ext_vector_type(8))) short bf16x8;
typedef __attribute__((ext_vector_type(4))) float f32x4;
typedef __attribute__((ext_vector_type(4))) unsigned short u16x4;

#define QSCALE 0.1803368801111832f   // 0.125 * log2(e); makes logits exp2-domain

__device__ __forceinline__ short f2bf(float f) {
    union { float f; unsigned u; } v; v.f = f;
    unsigned r = v.u + 0x7FFF + ((v.u >> 16) & 1);   // round-to-nearest-even
    return (short)(r >> 16);
}

// ---------------- K1: weight transpose + bf16 convert (coalesced) ----------------
__global__ __launch_bounds__(256) void wtrans(const float* __restrict__ Wq,
                                              const float* __restrict__ Wk,
                                              const float* __restrict__ Wv,
                                              short* __restrict__ Wt) {
    __shared__ short lds[64][66];
    int warr = blockIdx.x / 16;
    int d0 = (blockIdx.x % 16) * 64;
    const float* W = (warr == 0) ? Wq : (warr == 1) ? Wk : Wv;
    int rg = threadIdx.x >> 6;
    int c  = threadIdx.x & 63;
    #pragma unroll
    for (int p = 0; p < 16; ++p) {
        int d = p * 4 + rg;
        lds[d][c] = f2bf(W[(d0 + d) * 64 + c]);
    }
    __syncthreads();
    #pragma unroll
    for (int p = 0; p < 16; ++p) {
        int n = p * 4 + rg;
        Wt[(warr * 64 + n) * 1024 + d0 + c] = lds[c][n];
    }
}

// ---------------- K2: QKV projection, PF=8 register pipeline ----------------
// grid 512 blocks x 256 thr (4 waves). Block: M=16 rows, N=192, K=1024.
// wave wid=wc: cols n=wc*16+l15 in each of Q/K/V. All waves share the 16 x-rows (L1).
__global__ __launch_bounds__(256, 2) void qkv_proj(const float* __restrict__ x,
                                                   const short* __restrict__ Wt,
                                                   short* __restrict__ Q,
                                                   short* __restrict__ K,
                                                   short* __restrict__ Vt) {
    __shared__ short Vlds[16][72];
    int wid  = threadIdx.x >> 6;
    int lane = threadIdx.x & 63;
    int l15 = lane & 15, lg = lane >> 4;
    int mbase = blockIdx.x * 16;
    int row = mbase + l15;

    f32x4 acc0 = (f32x4){0.f, 0.f, 0.f, 0.f};
    f32x4 acc1 = acc0, acc2 = acc0;

    const float* xp0 = x + row * 1024 + lg * 8;
    const short* Wp0 = Wt + (wid * 16 + l15) * 1024 + lg * 8;
    const short* Wp1 = Wp0 + 64 * 1024;
    const short* Wp2 = Wp1 + 64 * 1024;

    constexpr int PF = 8;                 // pipeline depth: 8 iters of loads in flight
    float4 xa[PF], xb[PF];
    bf16x8 w0[PF], w1[PF], w2[PF];

    #pragma unroll
    for (int i = 0; i < PF; ++i) {
        int d0 = i * 32;
        xa[i] = *(const float4*)(xp0 + d0);
        xb[i] = *(const float4*)(xp0 + d0 + 4);
        w0[i] = *(const bf16x8*)(Wp0 + d0);
        w1[i] = *(const bf16x8*)(Wp1 + d0);
        w2[i] = *(const bf16x8*)(Wp2 + d0);
    }

    #pragma unroll
    for (int it = 0; it < 32; ++it) {
        int cur = it % PF;                // compile-time after full unroll
        bf16x8 a;
        a[0] = f2bf(xa[cur].x); a[1] = f2bf(xa[cur].y);
        a[2] = f2bf(xa[cur].z); a[3] = f2bf(xa[cur].w);
        a[4] = f2bf(xb[cur].x); a[5] = f2bf(xb[cur].y);
        a[6] = f2bf(xb[cur].z); a[7] = f2bf(xb[cur].w);
        acc0 = __builtin_amdgcn_mfma_f32_16x16x32_bf16(a, w0[cur], acc0, 0, 0, 0);
        acc1 = __builtin_amdgcn_mfma_f32_16x16x32_bf16(a, w1[cur], acc1, 0, 0, 0);
        acc2 = __builtin_amdgcn_mfma_f32_16x16x32_bf16(a, w2[cur], acc2, 0, 0, 0);
        if (it + PF < 32) {
            int d0 = (it + PF) * 32;
            xa[cur] = *(const float4*)(xp0 + d0);
            xb[cur] = *(const float4*)(xp0 + d0 + 4);
            w0[cur] = *(const bf16x8*)(Wp0 + d0);
            w1[cur] = *(const bf16x8*)(Wp1 + d0);
            w2[cur] = *(const bf16x8*)(Wp2 + d0);
        }
    }

    // epilogue: Q (scaled) and K direct (32B segments); V -> LDS transpose
    {
        int n = wid * 16 + l15;
        #pragma unroll
        for (int r = 0; r < 4; ++r) {
            int m = mbase + lg * 4 + r;
            Q[m * 64 + n] = f2bf(acc0[r] * QSCALE);
            K[m * 64 + n] = f2bf(acc1[r]);
            Vlds[lg * 4 + r][n] = f2bf(acc2[r]);
        }
    }
    __syncthreads();
    // Vt[(b*64+dk)*2048 + mbase + m]: 1024 elems, 256 thr, 4 each (8B stores)
    {
        int t = threadIdx.x;
        int dk = t >> 2;              // 0..63
        int m0 = (t & 3) * 4;         // 0,4,8,12
        u16x4 v;
        #pragma unroll
        for (int i = 0; i < 4; ++i) v[i] = (unsigned short)Vlds[m0 + i][dk];
        int b_ = mbase >> 11;
        int s_ = mbase & 2047;
        *(u16x4*)&Vt[(b_ * 64 + dk) * 2048 + s_ + m0] = v;
    }
}

// ---------------- K3: flash attention (round-7), swapped operands, split-KV ----------------
// grid = 4*128 = 512 blocks, 512 thr (8 waves). Each wave: same 16 queries, 256-key slice.
__global__ __launch_bounds__(512) void attn(const short* __restrict__ Q,
                                            const short* __restrict__ K,
                                            const short* __restrict__ Vt,
                                            float* __restrict__ out) {
    __shared__ float accw[8][16][68];
    __shared__ short P_lds[8][16][72];
    __shared__ float Mw[8][16];
    __shared__ float Lw[8][16];
    __shared__ float Ltot[16];

    int tid = threadIdx.x, wid = tid >> 6, lane = tid & 63;
    int l15 = lane & 15, lg = lane >> 4;
    int b_ = blockIdx.x >> 7;
    int q0 = (blockIdx.x & 127) * 16;
    const short* Kb = K + b_ * 2048 * 64;
    const short* Vb = Vt + b_ * 64 * 2048;

    const short* Qp = Q + (b_ * 2048 + q0 + l15) * 64 + lg * 8;
    bf16x8 bq0 = *(const bf16x8*)Qp;
    bf16x8 bq1 = *(const bf16x8*)(Qp + 32);

    f32x4 acc[4];
    #pragma unroll
    for (int t = 0; t < 4; ++t) acc[t] = (f32x4){0.f, 0.f, 0.f, 0.f};
    float m_run = -INFINITY, l_run = 0.f;

    int kv0 = wid * 256;
    for (int kv = kv0; kv < kv0 + 256; kv += 64) {
        f32x4 s[4];
        #pragma unroll
        for (int kt = 0; kt < 4; ++kt) {
            const short* Kp = Kb + (kv + kt * 16 + l15) * 64 + lg * 8;
            bf16x8 ak0 = *(const bf16x8*)Kp;
            bf16x8 ak1 = *(const bf16x8*)(Kp + 32);
            f32x4 z = (f32x4){0.f, 0.f, 0.f, 0.f};
            z = __builtin_amdgcn_mfma_f32_16x16x32_bf16(ak0, bq0, z, 0, 0, 0);
            s[kt] = __builtin_amdgcn_mfma_f32_16x16x32_bf16(ak1, bq1, z, 0, 0, 0);
        }

        float m01 = fmaxf(fmaxf(s[0][0], s[0][1]), fmaxf(s[0][2], s[0][3]));
        float m23 = fmaxf(fmaxf(s[1][0], s[1][1]), fmaxf(s[1][2], s[1][3]));
        float m45 = fmaxf(fmaxf(s[2][0], s[2][1]), fmaxf(s[2][2], s[2][3]));
        float m67 = fmaxf(fmaxf(s[3][0], s[3][1]), fmaxf(s[3][2], s[3][3]));
        float mt = fmaxf(fmaxf(m01, m23), fmaxf(m45, m67));
        mt = fmaxf(mt, __shfl_xor(mt, 16));
        mt = fmaxf(mt, __shfl_xor(mt, 32));
        float mn = fmaxf(m_run, mt);
        float c = exp2f(m_run - mn);
        m_run = mn;
        float rs = 0.f;
        #pragma unroll
        for (int kt = 0; kt < 4; ++kt)
            #pragma unroll
            for (int r = 0; r < 4; ++r) {
                float p = exp2f(s[kt][r] - mn);
                s[kt][r] = p;
                rs += p;
            }
        rs += __shfl_xor(rs, 16);
        rs += __shfl_xor(rs, 32);
        l_run = l_run * c + rs;
        #pragma unroll
        for (int t = 0; t < 4; ++t)
            #pragma unroll
            for (int r = 0; r < 4; ++r) acc[t][r] *= c;

        #pragma unroll
        for (int kt = 0; kt < 4; ++kt) {
            u16x4 h;
            h[0] = (unsigned short)f2bf(s[kt][0]);
            h[1] = (unsigned short)f2bf(s[kt][1]);
            h[2] = (unsigned short)f2bf(s[kt][2]);
            h[3] = (unsigned short)f2bf(s[kt][3]);
            *(u16x4*)&P_lds[wid][l15][kt * 16 + lg * 4] = h;
        }

        #pragma unroll
        for (int ps = 0; ps < 2; ++ps) {
            bf16x8 bp = *(const bf16x8*)&P_lds[wid][l15][ps * 32 + lg * 8];
            #pragma unroll
            for (int t = 0; t < 4; ++t) {
                const short* Vp = Vb + (t * 16 + l15) * 2048 + kv + ps * 32 + lg * 8;
                bf16x8 av = *(const bf16x8*)Vp;
                acc[t] = __builtin_amdgcn_mfma_f32_16x16x32_bf16(av, bp, acc[t], 0, 0, 0);
            }
        }
    }

    if (lg == 0) {
        Mw[wid][l15] = m_run;
        Lw[wid][l15] = l_run;
    }
    __syncthreads();

    float mtot = Mw[0][l15];
    #pragma unroll
    for (int w = 1; w < 8; ++w) mtot = fmaxf(mtot, Mw[w][l15]);
    float fac = exp2f(m_run - mtot);
    #pragma unroll
    for (int t = 0; t < 4; ++t) {
        f32x4 v = acc[t];
        v[0] *= fac; v[1] *= fac; v[2] *= fac; v[3] *= fac;
        *(f32x4*)&accw[wid][l15][t * 16 + lg * 4] = v;
    }

    if (wid == 0 && lg == 0) {
        float L = 0.f;
        #pragma unroll
        for (int w = 0; w < 8; ++w)
            L += Lw[w][l15] * exp2f(Mw[w][l15] - mtot);
        Ltot[l15] = L;
    }
    __syncthreads();

    #pragma unroll
    for (int j = 0; j < 2; ++j) {
        int o = tid + j * 512;
        int row = o >> 6, col = o & 63;
        float ssum = 0.f;
        #pragma unroll
        for (int w = 0; w < 8; ++w) ssum += accw[w][row][col];
        out[(b_ * 2048 + q0 + row) * 64 + col] = ssum / Ltot[row];
    }
}

extern "C" void kernel_launch(void* const* d_in, const int* in_sizes, int n_in,
                              void* d_out, int out_size, void* d_ws, size_t ws_size,
                              hipStream_t stream) {
    const float* x  = (const float*)d_in[0];
    const float* Wq = (const float*)d_in[1];
    const float* Wk = (const float*)d_in[2];
    const float* Wv = (const float*)d_in[3];
    float* out = (float*)d_out;

    char* ws = (char*)d_ws;
    short* Wt = (short*)ws;                              // 192*1024*2   = 393216 B
    short* Q  = (short*)(ws + 393216);                   // 8192*64*2    = 1048576 B
    short* K  = (short*)(ws + 393216 + 1048576);         // 1048576 B
    short* Vt = (short*)(ws + 393216 + 2 * 1048576);     // 1048576 B   (total ~3.4 MB)

    hipLaunchKernelGGL(wtrans,   dim3(48),  dim3(256), 0, stream, Wq, Wk, Wv, Wt);
    hipLaunchKernelGGL(qkv_proj, dim3(512), dim3(256), 0, stream, x, Wt, Q, K, Vt);
    hipLaunchKernelGGL(attn,     dim3(512), dim3(512), 0, stream, Q, K, Vt, out);
}

// Round 12
// 77.339 us; speedup vs baseline: 1.0224x; 1.0191x over previous
//
#include <hip/hip_runtime.h>
#include <hip/hip_bf16.h>

// Self-attention, fused QKV: x[4,2048,1024] f32, Wq/Wk/Wv[1024,64] f32 -> out[4,2048,64] f32
// bf16 MFMA (16x16x32), fp32 accumulation.
//   K1: W -> Wt bf16 [192][1024] via LDS tile-transpose (coalesced both sides)
//   K2: QKV projection as canonical LDS-staged GEMM: coalesced cooperative staging
//       (fixes the 16-transaction/load scatter that made rounds 2-11 latency-bound),
//       padded LDS (+8 shorts -> conflict-free ds_read_b128), M=32 x N=96 x BK=64.
//   K3: flash attention (round-7 proven): swapped operands (lane owns one query),
//       split-KV x8, no barriers in KV loop, deterministic combine.

typedef __attribute__((ext_vector_type(8))) short bf16x8;
typedef __attribute__((ext_vector_type(4))) float f32x4;
typedef __attribute__((ext_vector_type(4))) unsigned short u16x4;

#define QSCALE 0.1803368801111832f   // 0.125 * log2(e); makes logits exp2-domain

__device__ __forceinline__ short f2bf(float f) {
    union { float f; unsigned u; } v; v.f = f;
    unsigned r = v.u + 0x7FFF + ((v.u >> 16) & 1);   // round-to-nearest-even
    return (short)(r >> 16);
}

// ---------------- K1: weight transpose + bf16 convert (coalesced) ----------------
__global__ __launch_bounds__(256) void wtrans(const float* __restrict__ Wq,
                                              const float* __restrict__ Wk,
                                              const float* __restrict__ Wv,
                                              short* __restrict__ Wt) {
    __shared__ short lds[64][66];
    int warr = blockIdx.x / 16;
    int d0 = (blockIdx.x % 16) * 64;
    const float* W = (warr == 0) ? Wq : (warr == 1) ? Wk : Wv;
    int rg = threadIdx.x >> 6;
    int c  = threadIdx.x & 63;
    #pragma unroll
    for (int p = 0; p < 16; ++p) {
        int d = p * 4 + rg;
        lds[d][c] = f2bf(W[(d0 + d) * 64 + c]);
    }
    __syncthreads();
    #pragma unroll
    for (int p = 0; p < 16; ++p) {
        int n = p * 4 + rg;
        Wt[(warr * 64 + n) * 1024 + d0 + c] = lds[c][n];
    }
}

// ---------------- K2: QKV projection, LDS-staged GEMM ----------------
// grid = 256 M-tiles x 2 N-halves = 512 blocks, 256 thr (4 waves).
// Tile: M=32 rows x N=96 cols (nhalf 0: QKV cols 0-95; nhalf 1: cols 96-191), BK=64.
// Wave (wr,wn)=(wid>>1, wid&1): rows wr*16..+15, frags wn*3..+2.
__global__ __launch_bounds__(256) void qkv_proj(const float* __restrict__ x,
                                                const short* __restrict__ Wt,
                                                short* __restrict__ Q,
                                                short* __restrict__ K,
                                                short* __restrict__ Vt) {
    __shared__ short A_lds[32][72];   // [m][k], +8 pad -> 144B stride, conflict-free
    __shared__ short B_lds[96][72];   // [n][k]
    int tid = threadIdx.x;
    int wid = tid >> 6, lane = tid & 63;
    int l15 = lane & 15, lg = lane >> 4;
    int wr = wid >> 1, wn = wid & 1;
    int mbase = (blockIdx.x >> 1) * 32;
    int nbase = (blockIdx.x & 1) * 96;

    f32x4 acc[3];
    #pragma unroll
    for (int f = 0; f < 3; ++f) acc[f] = (f32x4){0.f, 0.f, 0.f, 0.f};

    for (int k0 = 0; k0 < 1024; k0 += 64) {
        __syncthreads();   // previous step's LDS reads done before overwrite
        // stage A: 32 rows x 64 floats -> bf16. 512 float4 chunks, 2/thread.
        // idx -> row=idx>>4, c4=idx&15: 16 consecutive threads read 256B of one row.
        #pragma unroll
        for (int j = 0; j < 2; ++j) {
            int idx = tid + j * 256;
            int r = idx >> 4, c4 = idx & 15;
            float4 v = *(const float4*)(x + (mbase + r) * 1024 + k0 + c4 * 4);
            u16x4 h;
            h[0] = (unsigned short)f2bf(v.x);
            h[1] = (unsigned short)f2bf(v.y);
            h[2] = (unsigned short)f2bf(v.z);
            h[3] = (unsigned short)f2bf(v.w);
            *(u16x4*)&A_lds[r][c4 * 4] = h;
        }
        // stage B: 96 rows x 64 shorts (128B). 768 16B chunks, 3/thread.
        #pragma unroll
        for (int j = 0; j < 3; ++j) {
            int idx = tid + j * 256;
            int r = idx >> 3, c8 = idx & 7;
            bf16x8 wv = *(const bf16x8*)(Wt + (nbase + r) * 1024 + k0 + c8 * 8);
            *(bf16x8*)&B_lds[r][c8 * 8] = wv;
        }
        __syncthreads();
        // compute: per wave 2 A-frags, 6 B-frags, 6 MFMA
        bf16x8 a0 = *(const bf16x8*)&A_lds[wr * 16 + l15][lg * 8];
        bf16x8 a1 = *(const bf16x8*)&A_lds[wr * 16 + l15][32 + lg * 8];
        #pragma unroll
        for (int f = 0; f < 3; ++f) {
            int nr = (wn * 3 + f) * 16 + l15;
            bf16x8 b0 = *(const bf16x8*)&B_lds[nr][lg * 8];
            bf16x8 b1 = *(const bf16x8*)&B_lds[nr][32 + lg * 8];
            acc[f] = __builtin_amdgcn_mfma_f32_16x16x32_bf16(a0, b0, acc[f], 0, 0, 0);
            acc[f] = __builtin_amdgcn_mfma_f32_16x16x32_bf16(a1, b1, acc[f], 0, 0, 0);
        }
    }
    __syncthreads();   // done reading A_lds; reuse it for V transpose below

    // epilogue. n_global = nbase + (wn*3+f)*16 + l15; m = mbase + wr*16 + lg*4 + r.
    #pragma unroll
    for (int f = 0; f < 3; ++f) {
        int n = nbase + (wn * 3 + f) * 16 + l15;
        #pragma unroll
        for (int r = 0; r < 4; ++r) {
            int ml = wr * 16 + lg * 4 + r;
            int m = mbase + ml;
            float v = acc[f][r];
            if (n < 64) {
                Q[m * 64 + n] = f2bf(v * QSCALE);
            } else if (n < 128) {
                K[m * 64 + (n - 64)] = f2bf(v);
            } else {
                A_lds[ml][n - 128] = f2bf(v);   // Vlds[m_local][dk]
            }
        }
    }
    if (nbase == 96) {
        __syncthreads();
        // Vt[(b*64+dk)*2048 + mbase + m]: 64 dk x 32 m. thread: dk=t>>2, m0=(t&3)*8.
        int dk = tid >> 2;
        int m0 = (tid & 3) * 8;
        int b_ = mbase >> 11;
        int s_ = mbase & 2047;
        #pragma unroll
        for (int j = 0; j < 2; ++j) {
            u16x4 v;
            #pragma unroll
            for (int i = 0; i < 4; ++i) v[i] = (unsigned short)A_lds[m0 + j * 4 + i][dk];
            *(u16x4*)&Vt[(b_ * 64 + dk) * 2048 + s_ + m0 + j * 4] = v;
        }
    }
}

// ---------------- K3: flash attention (round-7), swapped operands, split-KV ----------------
// grid = 4*128 = 512 blocks, 512 thr (8 waves). Each wave: same 16 queries, 256-key slice.
__global__ __launch_bounds__(512) void attn(const short* __restrict__ Q,
                                            const short* __restrict__ K,
                                            const short* __restrict__ Vt,
                                            float* __restrict__ out) {
    __shared__ float accw[8][16][68];
    __shared__ short P_lds[8][16][72];
    __shared__ float Mw[8][16];
    __shared__ float Lw[8][16];
    __shared__ float Ltot[16];

    int tid = threadIdx.x, wid = tid >> 6, lane = tid & 63;
    int l15 = lane & 15, lg = lane >> 4;
    int b_ = blockIdx.x >> 7;
    int q0 = (blockIdx.x & 127) * 16;
    const short* Kb = K + b_ * 2048 * 64;
    const short* Vb = Vt + b_ * 64 * 2048;

    const short* Qp = Q + (b_ * 2048 + q0 + l15) * 64 + lg * 8;
    bf16x8 bq0 = *(const bf16x8*)Qp;
    bf16x8 bq1 = *(const bf16x8*)(Qp + 32);

    f32x4 acc[4];
    #pragma unroll
    for (int t = 0; t < 4; ++t) acc[t] = (f32x4){0.f, 0.f, 0.f, 0.f};
    float m_run = -INFINITY, l_run = 0.f;

    int kv0 = wid * 256;
    for (int kv = kv0; kv < kv0 + 256; kv += 64) {
        f32x4 s[4];
        #pragma unroll
        for (int kt = 0; kt < 4; ++kt) {
            const short* Kp = Kb + (kv + kt * 16 + l15) * 64 + lg * 8;
            bf16x8 ak0 = *(const bf16x8*)Kp;
            bf16x8 ak1 = *(const bf16x8*)(Kp + 32);
            f32x4 z = (f32x4){0.f, 0.f, 0.f, 0.f};
            z = __builtin_amdgcn_mfma_f32_16x16x32_bf16(ak0, bq0, z, 0, 0, 0);
            s[kt] = __builtin_amdgcn_mfma_f32_16x16x32_bf16(ak1, bq1, z, 0, 0, 0);
        }

        float m01 = fmaxf(fmaxf(s[0][0], s[0][1]), fmaxf(s[0][2], s[0][3]));
        float m23 = fmaxf(fmaxf(s[1][0], s[1][1]), fmaxf(s[1][2], s[1][3]));
        float m45 = fmaxf(fmaxf(s[2][0], s[2][1]), fmaxf(s[2][2], s[2][3]));
        float m67 = fmaxf(fmaxf(s[3][0], s[3][1]), fmaxf(s[3][2], s[3][3]));
        float mt = fmaxf(fmaxf(m01, m23), fmaxf(m45, m67));
        mt = fmaxf(mt, __shfl_xor(mt, 16));
        mt = fmaxf(mt, __shfl_xor(mt, 32));
        float mn = fmaxf(m_run, mt);
        float c = exp2f(m_run - mn);
        m_run = mn;
        float rs = 0.f;
        #pragma unroll
        for (int kt = 0; kt < 4; ++kt)
            #pragma unroll
            for (int r = 0; r < 4; ++r) {
                float p = exp2f(s[kt][r] - mn);
                s[kt][r] = p;
                rs += p;
            }
        rs += __shfl_xor(rs, 16);
        rs += __shfl_xor(rs, 32);
        l_run = l_run * c + rs;
        #pragma unroll
        for (int t = 0; t < 4; ++t)
            #pragma unroll
            for (int r = 0; r < 4; ++r) acc[t][r] *= c;

        #pragma unroll
        for (int kt = 0; kt < 4; ++kt) {
            u16x4 h;
            h[0] = (unsigned short)f2bf(s[kt][0]);
            h[1] = (unsigned short)f2bf(s[kt][1]);
            h[2] = (unsigned short)f2bf(s[kt][2]);
            h[3] = (unsigned short)f2bf(s[kt][3]);
            *(u16x4*)&P_lds[wid][l15][kt * 16 + lg * 4] = h;
        }

        #pragma unroll
        for (int ps = 0; ps < 2; ++ps) {
            bf16x8 bp = *(const bf16x8*)&P_lds[wid][l15][ps * 32 + lg * 8];
            #pragma unroll
            for (int t = 0; t < 4; ++t) {
                const short* Vp = Vb + (t * 16 + l15) * 2048 + kv + ps * 32 + lg * 8;
                bf16x8 av = *(const bf16x8*)Vp;
                acc[t] = __builtin_amdgcn_mfma_f32_16x16x32_bf16(av, bp, acc[t], 0, 0, 0);
            }
        }
    }

    if (lg == 0) {
        Mw[wid][l15] = m_run;
        Lw[wid][l15] = l_run;
    }
    __syncthreads();

    float mtot = Mw[0][l15];
    #pragma unroll
    for (int w = 1; w < 8; ++w) mtot = fmaxf(mtot, Mw[w][l15]);
    float fac = exp2f(m_run - mtot);
    #pragma unroll
    for (int t = 0; t < 4; ++t) {
        f32x4 v = acc[t];
        v[0] *= fac; v[1] *= fac; v[2] *= fac; v[3] *= fac;
        *(f32x4*)&accw[wid][l15][t * 16 + lg * 4] = v;
    }

    if (wid == 0 && lg == 0) {
        float L = 0.f;
        #pragma unroll
        for (int w = 0; w < 8; ++w)
            L += Lw[w][l15] * exp2f(Mw[w][l15] - mtot);
        Ltot[l15] = L;
    }
    __syncthreads();

    #pragma unroll
    for (int j = 0; j < 2; ++j) {
        int o = tid + j * 512;
        int row = o >> 6, col = o & 63;
        float ssum = 0.f;
        #pragma unroll
        for (int w = 0; w < 8; ++w) ssum += accw[w][row][col];
        out[(b_ * 2048 + q0 + row) * 64 + col] = ssum / Ltot[row];
    }
}

extern "C" void kernel_launch(void* const* d_in, const int* in_sizes, int n_in,
                              void* d_out, int out_size, void* d_ws, size_t ws_size,
                              hipStream_t stream) {
    const float* x  = (const float*)d_in[0];
    const float* Wq = (const float*)d_in[1];
    const float* Wk = (const float*)d_in[2];
    const float* Wv = (const float*)d_in[3];
    float* out = (float*)d_out;

    char* ws = (char*)d_ws;
    short* Wt = (short*)ws;                              // 192*1024*2   = 393216 B
    short* Q  = (short*)(ws + 393216);                   // 8192*64*2    = 1048576 B
    short* K  = (short*)(ws + 393216 + 1048576);         // 1048576 B
    short* Vt = (short*)(ws + 393216 + 2 * 1048576);     // 1048576 B   (total ~3.4 MB)

    hipLaunchKernelGGL(wtrans,   dim3(48),   dim3(256), 0, stream, Wq, Wk, Wv, Wt);
    hipLaunchKernelGGL(qkv_proj, dim3(512),  dim3(256), 0, stream, x, Wt, Q, K, Vt);
    hipLaunchKernelGGL(attn,     dim3(512),  dim3(512), 0, stream, Q, K, Vt, out);
}

// Round 13
// 73.140 us; speedup vs baseline: 1.0811x; 1.0574x over previous
//
#include <hip/hip_runtime.h>
#include <hip/hip_bf16.h>

// Self-attention, fused QKV: x[4,2048,1024] f32, Wq/Wk/Wv[1024,64] f32 -> out[4,2048,64] f32
// bf16 MFMA (16x16x32), fp32 accumulation.
//   K1: W -> Wt bf16 [192][1024] via LDS tile-transpose (coalesced both sides)
//   K2: QKV projection = ROUND-1 structure (empirically fastest: direct loads, no
//       K-loop barriers, 6 MFMA + 8 loads/iter/wave, 1024 waves, x read 2x) with
//       QSCALE folded into Q and V epilogue via LDS -> coalesced Vt stores.
//   K3: flash attention (round-7 proven): swapped operands (lane owns one query),
//       split-KV x8, no barriers in KV loop, deterministic combine.

typedef __attribute__((ext_vector_type(8))) short bf16x8;
typedef __attribute__((ext_vector_type(4))) float f32x4;
typedef __attribute__((ext_vector_type(4))) unsigned short u16x4;

#define QSCALE 0.1803368801111832f   // 0.125 * log2(e); makes logits exp2-domain

__device__ __forceinline__ short f2bf(float f) {
    union { float f; unsigned u; } v; v.f = f;
    unsigned r = v.u + 0x7FFF + ((v.u >> 16) & 1);   // round-to-nearest-even
    return (short)(r >> 16);
}

// ---------------- K1: weight transpose + bf16 convert (coalesced) ----------------
__global__ __launch_bounds__(256) void wtrans(const float* __restrict__ Wq,
                                              const float* __restrict__ Wk,
                                              const float* __restrict__ Wv,
                                              short* __restrict__ Wt) {
    __shared__ short lds[64][66];
    int warr = blockIdx.x / 16;
    int d0 = (blockIdx.x % 16) * 64;
    const float* W = (warr == 0) ? Wq : (warr == 1) ? Wk : Wv;
    int rg = threadIdx.x >> 6;
    int c  = threadIdx.x & 63;
    #pragma unroll
    for (int p = 0; p < 16; ++p) {
        int d = p * 4 + rg;
        lds[d][c] = f2bf(W[(d0 + d) * 64 + c]);
    }
    __syncthreads();
    #pragma unroll
    for (int p = 0; p < 16; ++p) {
        int n = p * 4 + rg;
        Wt[(warr * 64 + n) * 1024 + d0 + c] = lds[c][n];
    }
}

// ---------------- K2: QKV projection (round-1 structure) ----------------
// grid 256 blocks x 256 thr (4 waves). Block tile: 32 rows x 192 cols, K=1024.
// wave w: rows mbase+(w&1)*16, cols (w>>1)*96 (6 n-frags of 16). x read 2x total.
// No barriers in the K loop; 6 MFMA + 8 independent loads per iteration.
__global__ __launch_bounds__(256) void qkv_proj(const float* __restrict__ x,
                                                const short* __restrict__ Wt,
                                                short* __restrict__ Q,
                                                short* __restrict__ K,
                                                short* __restrict__ Vt) {
    __shared__ short Vlds[32][72];
    int wid  = threadIdx.x >> 6;
    int lane = threadIdx.x & 63;
    int l15 = lane & 15, lg = lane >> 4;
    int mbase = blockIdx.x * 32 + (wid & 1) * 16;
    int nbase = (wid >> 1) * 96;
    int row = mbase + l15;

    f32x4 acc[6];
    #pragma unroll
    for (int t = 0; t < 6; ++t) acc[t] = (f32x4){0.f, 0.f, 0.f, 0.f};

    for (int d0 = 0; d0 < 1024; d0 += 32) {
        const float* xp = x + row * 1024 + d0 + lg * 8;
        float4 x0 = *(const float4*)xp;
        float4 x1 = *(const float4*)(xp + 4);
        bf16x8 a;
        a[0] = f2bf(x0.x); a[1] = f2bf(x0.y); a[2] = f2bf(x0.z); a[3] = f2bf(x0.w);
        a[4] = f2bf(x1.x); a[5] = f2bf(x1.y); a[6] = f2bf(x1.z); a[7] = f2bf(x1.w);
        #pragma unroll
        for (int t = 0; t < 6; ++t) {
            int n = nbase + t * 16 + l15;
            bf16x8 b = *(const bf16x8*)(Wt + n * 1024 + d0 + lg * 8);
            acc[t] = __builtin_amdgcn_mfma_f32_16x16x32_bf16(a, b, acc[t], 0, 0, 0);
        }
    }

    // epilogue: Q (scaled), K direct; V -> Vlds (local rows 0-31)
    #pragma unroll
    for (int t = 0; t < 6; ++t) {
        int n = nbase + t * 16 + l15;
        #pragma unroll
        for (int r = 0; r < 4; ++r) {
            int ml = (wid & 1) * 16 + lg * 4 + r;
            int m = blockIdx.x * 32 + ml;
            float v = acc[t][r];
            if (n < 64) {
                Q[m * 64 + n] = f2bf(v * QSCALE);
            } else if (n < 128) {
                K[m * 64 + (n - 64)] = f2bf(v);
            } else {
                Vlds[ml][n - 128] = f2bf(v);
            }
        }
    }
    __syncthreads();
    // Vt[(b*64+dk)*2048 + mb + m]: 64 dk x 32 m, 256 thr x 8 shorts (2x u16x4)
    {
        int tid = threadIdx.x;
        int dk = tid >> 2;            // 0..63
        int m0 = (tid & 3) * 8;       // 0,8,16,24
        int mb = blockIdx.x * 32;
        int b_ = mb >> 11;
        int s_ = mb & 2047;
        #pragma unroll
        for (int j = 0; j < 2; ++j) {
            u16x4 v;
            #pragma unroll
            for (int i = 0; i < 4; ++i) v[i] = (unsigned short)Vlds[m0 + j * 4 + i][dk];
            *(u16x4*)&Vt[(b_ * 64 + dk) * 2048 + s_ + m0 + j * 4] = v;
        }
    }
}

// ---------------- K3: flash attention (round-7), swapped operands, split-KV ----------------
// grid = 4*128 = 512 blocks, 512 thr (8 waves). Each wave: same 16 queries, 256-key slice.
__global__ __launch_bounds__(512) void attn(const short* __restrict__ Q,
                                            const short* __restrict__ K,
                                            const short* __restrict__ Vt,
                                            float* __restrict__ out) {
    __shared__ float accw[8][16][68];
    __shared__ short P_lds[8][16][72];
    __shared__ float Mw[8][16];
    __shared__ float Lw[8][16];
    __shared__ float Ltot[16];

    int tid = threadIdx.x, wid = tid >> 6, lane = tid & 63;
    int l15 = lane & 15, lg = lane >> 4;
    int b_ = blockIdx.x >> 7;
    int q0 = (blockIdx.x & 127) * 16;
    const short* Kb = K + b_ * 2048 * 64;
    const short* Vb = Vt + b_ * 64 * 2048;

    const short* Qp = Q + (b_ * 2048 + q0 + l15) * 64 + lg * 8;
    bf16x8 bq0 = *(const bf16x8*)Qp;
    bf16x8 bq1 = *(const bf16x8*)(Qp + 32);

    f32x4 acc[4];
    #pragma unroll
    for (int t = 0; t < 4; ++t) acc[t] = (f32x4){0.f, 0.f, 0.f, 0.f};
    float m_run = -INFINITY, l_run = 0.f;

    int kv0 = wid * 256;
    for (int kv = kv0; kv < kv0 + 256; kv += 64) {
        f32x4 s[4];
        #pragma unroll
        for (int kt = 0; kt < 4; ++kt) {
            const short* Kp = Kb + (kv + kt * 16 + l15) * 64 + lg * 8;
            bf16x8 ak0 = *(const bf16x8*)Kp;
            bf16x8 ak1 = *(const bf16x8*)(Kp + 32);
            f32x4 z = (f32x4){0.f, 0.f, 0.f, 0.f};
            z = __builtin_amdgcn_mfma_f32_16x16x32_bf16(ak0, bq0, z, 0, 0, 0);
            s[kt] = __builtin_amdgcn_mfma_f32_16x16x32_bf16(ak1, bq1, z, 0, 0, 0);
        }

        float m01 = fmaxf(fmaxf(s[0][0], s[0][1]), fmaxf(s[0][2], s[0][3]));
        float m23 = fmaxf(fmaxf(s[1][0], s[1][1]), fmaxf(s[1][2], s[1][3]));
        float m45 = fmaxf(fmaxf(s[2][0], s[2][1]), fmaxf(s[2][2], s[2][3]));
        float m67 = fmaxf(fmaxf(s[3][0], s[3][1]), fmaxf(s[3][2], s[3][3]));
        float mt = fmaxf(fmaxf(m01, m23), fmaxf(m45, m67));
        mt = fmaxf(mt, __shfl_xor(mt, 16));
        mt = fmaxf(mt, __shfl_xor(mt, 32));
        float mn = fmaxf(m_run, mt);
        float c = exp2f(m_run - mn);
        m_run = mn;
        float rs = 0.f;
        #pragma unroll
        for (int kt = 0; kt < 4; ++kt)
            #pragma unroll
            for (int r = 0; r < 4; ++r) {
                float p = exp2f(s[kt][r] - mn);
                s[kt][r] = p;
                rs += p;
            }
        rs += __shfl_xor(rs, 16);
        rs += __shfl_xor(rs, 32);
        l_run = l_run * c + rs;
        #pragma unroll
        for (int t = 0; t < 4; ++t)
            #pragma unroll
            for (int r = 0; r < 4; ++r) acc[t][r] *= c;

        #pragma unroll
        for (int kt = 0; kt < 4; ++kt) {
            u16x4 h;
            h[0] = (unsigned short)f2bf(s[kt][0]);
            h[1] = (unsigned short)f2bf(s[kt][1]);
            h[2] = (unsigned short)f2bf(s[kt][2]);
            h[3] = (unsigned short)f2bf(s[kt][3]);
            *(u16x4*)&P_lds[wid][l15][kt * 16 + lg * 4] = h;
        }

        #pragma unroll
        for (int ps = 0; ps < 2; ++ps) {
            bf16x8 bp = *(const bf16x8*)&P_lds[wid][l15][ps * 32 + lg * 8];
            #pragma unroll
            for (int t = 0; t < 4; ++t) {
                const short* Vp = Vb + (t * 16 + l15) * 2048 + kv + ps * 32 + lg * 8;
                bf16x8 av = *(const bf16x8*)Vp;
                acc[t] = __builtin_amdgcn_mfma_f32_16x16x32_bf16(av, bp, acc[t], 0, 0, 0);
            }
        }
    }

    if (lg == 0) {
        Mw[wid][l15] = m_run;
        Lw[wid][l15] = l_run;
    }
    __syncthreads();

    float mtot = Mw[0][l15];
    #pragma unroll
    for (int w = 1; w < 8; ++w) mtot = fmaxf(mtot, Mw[w][l15]);
    float fac = exp2f(m_run - mtot);
    #pragma unroll
    for (int t = 0; t < 4; ++t) {
        f32x4 v = acc[t];
        v[0] *= fac; v[1] *= fac; v[2] *= fac; v[3] *= fac;
        *(f32x4*)&accw[wid][l15][t * 16 + lg * 4] = v;
    }

    if (wid == 0 && lg == 0) {
        float L = 0.f;
        #pragma unroll
        for (int w = 0; w < 8; ++w)
            L += Lw[w][l15] * exp2f(Mw[w][l15] - mtot);
        Ltot[l15] = L;
    }
    __syncthreads();

    #pragma unroll
    for (int j = 0; j < 2; ++j) {
        int o = tid + j * 512;
        int row = o >> 6, col = o & 63;
        float ssum = 0.f;
        #pragma unroll
        for (int w = 0; w < 8; ++w) ssum += accw[w][row][col];
        out[(b_ * 2048 + q0 + row) * 64 + col] = ssum / Ltot[row];
    }
}

extern "C" void kernel_launch(void* const* d_in, const int* in_sizes, int n_in,
                              void* d_out, int out_size, void* d_ws, size_t ws_size,
                              hipStream_t stream) {
    const float* x  = (const float*)d_in[0];
    const float* Wq = (const float*)d_in[1];
    const float* Wk = (const float*)d_in[2];
    const float* Wv = (const float*)d_in[3];
    float* out = (float*)d_out;

    char* ws = (char*)d_ws;
    short* Wt = (short*)ws;                              // 192*1024*2   = 393216 B
    short* Q  = (short*)(ws + 393216);                   // 8192*64*2    = 1048576 B
    short* K  = (short*)(ws + 393216 + 1048576);         // 1048576 B
    short* Vt = (short*)(ws + 393216 + 2 * 1048576);     // 1048576 B   (total ~3.4 MB)

    hipLaunchKernelGGL(wtrans,   dim3(48),  dim3(256), 0, stream, Wq, Wk, Wv, Wt);
    hipLaunchKernelGGL(qkv_proj, dim3(256), dim3(256), 0, stream, x, Wt, Q, K, Vt);
    hipLaunchKernelGGL(attn,     dim3(512), dim3(512), 0, stream, Q, K, Vt, out);
}

// Round 14
// 68.149 us; speedup vs baseline: 1.1602x; 1.0732x over previous
//
#include <hip/hip_runtime.h>
#include <hip/hip_bf16.h>

// Self-attention, fused QKV: x[4,2048,1024] f32, Wq/Wk/Wv[1024,64] f32 -> out[4,2048,64] f32
// bf16 MFMA (16x16x32), fp32 accumulation.
//   K1: W -> Wt bf16 [192][1024] via LDS tile-transpose (coalesced both sides)
//   K2: QKV projection via global_load_lds double-buffered GEMM (2-phase schedule):
//       HW async queue gives ~40 loads in flight/wave vs ~4 with VGPR paths -- the
//       in-flight-bytes fix for the 43us plateau of rounds 1-13. XOR-swizzled
//       source + swizzled ds_read (linear LDS dest, rule #21). M=32 x N=96 x BK=64.
//   K3: flash attention (round-7 proven): swapped operands (lane owns one query),
//       split-KV x8, no barriers in KV loop, deterministic combine.

typedef __attribute__((ext_vector_type(8))) short bf16x8;
typedef __attribute__((ext_vector_type(4))) float f32x4;
typedef __attribute__((ext_vector_type(4))) unsigned short u16x4;

#define QSCALE 0.1803368801111832f   // 0.125 * log2(e); makes logits exp2-domain

__device__ __forceinline__ short f2bf(float f) {
    union { float f; unsigned u; } v; v.f = f;
    unsigned r = v.u + 0x7FFF + ((v.u >> 16) & 1);   // round-to-nearest-even
    return (short)(r >> 16);
}

__device__ __forceinline__ void gload16(const void* src, void* dst) {
    __builtin_amdgcn_global_load_lds(
        (const __attribute__((address_space(1))) unsigned int*)src,
        (__attribute__((address_space(3))) unsigned int*)dst, 16, 0, 0);
}

// ---------------- K1: weight transpose + bf16 convert (coalesced) ----------------
__global__ __launch_bounds__(256) void wtrans(const float* __restrict__ Wq,
                                              const float* __restrict__ Wk,
                                              const float* __restrict__ Wv,
                                              short* __restrict__ Wt) {
    __shared__ short lds[64][66];
    int warr = blockIdx.x / 16;
    int d0 = (blockIdx.x % 16) * 64;
    const float* W = (warr == 0) ? Wq : (warr == 1) ? Wk : Wv;
    int rg = threadIdx.x >> 6;
    int c  = threadIdx.x & 63;
    #pragma unroll
    for (int p = 0; p < 16; ++p) {
        int d = p * 4 + rg;
        lds[d][c] = f2bf(W[(d0 + d) * 64 + c]);
    }
    __syncthreads();
    #pragma unroll
    for (int p = 0; p < 16; ++p) {
        int n = p * 4 + rg;
        Wt[(warr * 64 + n) * 1024 + d0 + c] = lds[c][n];
    }
}

// ---------------- K2: QKV projection, global_load_lds 2-phase GEMM ----------------
// grid = 256 M-tiles x 2 N-halves = 512 blocks, 256 thr (4 waves).
// Tile M=32 x N=96, BK=64 (16 K-steps). LDS buffer per phase (20KB):
//   A: 32 rows x 256B f32 (8 chunks of 1KB), swizzled in 32B slots: s32' = s32 ^ (row&7)
//   B: 96 rows x 128B bf16 (12 chunks),      swizzled in 16B slots: s'   = s   ^ (row&7)
// Stager writes linear (gload_lds lane*16), source pre-swizzled; reader applies same XOR.
__global__ __launch_bounds__(256) void qkv_proj(const float* __restrict__ x,
                                                const short* __restrict__ Wt,
                                                short* __restrict__ Q,
                                                short* __restrict__ K,
                                                short* __restrict__ Vt) {
    __shared__ char stage_lds[2][20 * 1024];
    __shared__ short Vlds[32][72];

    int tid = threadIdx.x;
    int wid = tid >> 6, lane = tid & 63;
    int l15 = lane & 15, lg = lane >> 4;
    int wr = wid >> 1, wn = wid & 1;
    int mbase = (blockIdx.x >> 1) * 32;
    int nbase = (blockIdx.x & 1) * 96;

    // per-thread staging source precompute (chunk layout fixed across steps)
    // chunks 0..7: A (4 rows x 256B each); 8..19: B (8 rows x 128B each)
    int a_rows[2], a_soff[2];   // j=0,1 -> chunks wid, wid+4 (both A)
    #pragma unroll
    for (int j = 0; j < 2; ++j) {
        int chunk = wid + j * 4;
        int row = chunk * 4 + (lane >> 4);
        int slot16 = lane & 15;
        int s32 = slot16 >> 1, h16 = slot16 & 1;
        int s32s = s32 ^ (row & 7);
        a_rows[j] = row;
        a_soff[j] = (mbase + row) * 1024 + s32s * 8 + h16 * 4;   // float offset
    }
    int b_soff[3];              // j=2,3,4 -> chunks wid+8, wid+12, wid+16 (B)
    #pragma unroll
    for (int j = 0; j < 3; ++j) {
        int cb = wid + j * 4;   // 0..11
        int row = cb * 8 + (lane >> 3);
        int slot = lane & 7;
        int ss = slot ^ (row & 7);
        b_soff[j] = (nbase + row) * 1024 + ss * 8;               // short offset
    }

    f32x4 acc[3];
    #pragma unroll
    for (int f = 0; f < 3; ++f) acc[f] = (f32x4){0.f, 0.f, 0.f, 0.f};

    // prologue: stage step 0 into buffer 0
    {
        char* base = &stage_lds[0][0];
        #pragma unroll
        for (int j = 0; j < 2; ++j)
            gload16(x + a_soff[j], base + (wid + j * 4) * 1024);
        #pragma unroll
        for (int j = 0; j < 3; ++j)
            gload16(Wt + b_soff[j], base + 8192 + (wid + j * 4) * 1024);
    }
    __syncthreads();

    for (int t = 0; t < 16; ++t) {
        int sb = t & 1;
        if (t < 15) {
            int k0 = (t + 1) * 64;
            char* base = &stage_lds[sb ^ 1][0];
            #pragma unroll
            for (int j = 0; j < 2; ++j)
                gload16(x + a_soff[j] + k0, base + (wid + j * 4) * 1024);
            #pragma unroll
            for (int j = 0; j < 3; ++j)
                gload16(Wt + b_soff[j] + k0, base + 8192 + (wid + j * 4) * 1024);
        }
        const char* Ab = &stage_lds[sb][0];
        const char* Bb = &stage_lds[sb][8192];
        int arow = wr * 16 + l15;
        #pragma unroll
        for (int h = 0; h < 2; ++h) {
            // A frag: f32 -> bf16 after swizzled ds_read
            int s32s = (h * 4 + lg) ^ (arow & 7);
            const float4* ap = (const float4*)(Ab + arow * 256 + s32s * 32);
            float4 f0 = ap[0];
            float4 f1 = ap[1];
            bf16x8 a;
            a[0] = f2bf(f0.x); a[1] = f2bf(f0.y); a[2] = f2bf(f0.z); a[3] = f2bf(f0.w);
            a[4] = f2bf(f1.x); a[5] = f2bf(f1.y); a[6] = f2bf(f1.z); a[7] = f2bf(f1.w);
            #pragma unroll
            for (int f = 0; f < 3; ++f) {
                int brow = (wn * 3 + f) * 16 + l15;
                int ss = (h * 4 + lg) ^ (brow & 7);
                bf16x8 b = *(const bf16x8*)(Bb + brow * 128 + ss * 16);
                acc[f] = __builtin_amdgcn_mfma_f32_16x16x32_bf16(a, b, acc[f], 0, 0, 0);
            }
        }
        __syncthreads();
    }

    // epilogue. n = nbase + (wn*3+f)*16 + l15; m = mbase + wr*16 + lg*4 + r.
    #pragma unroll
    for (int f = 0; f < 3; ++f) {
        int n = nbase + (wn * 3 + f) * 16 + l15;
        #pragma unroll
        for (int r = 0; r < 4; ++r) {
            int ml = wr * 16 + lg * 4 + r;
            int m = mbase + ml;
            float v = acc[f][r];
            if (n < 64) {
                Q[m * 64 + n] = f2bf(v * QSCALE);
            } else if (n < 128) {
                K[m * 64 + (n - 64)] = f2bf(v);
            } else {
                Vlds[ml][n - 128] = f2bf(v);
            }
        }
    }
    if (nbase == 96) {    // block-uniform branch: barrier legal
        __syncthreads();
        int dk = tid >> 2;
        int m0 = (tid & 3) * 8;
        int b_ = mbase >> 11;
        int s_ = mbase & 2047;
        #pragma unroll
        for (int j = 0; j < 2; ++j) {
            u16x4 v;
            #pragma unroll
            for (int i = 0; i < 4; ++i) v[i] = (unsigned short)Vlds[m0 + j * 4 + i][dk];
            *(u16x4*)&Vt[(b_ * 64 + dk) * 2048 + s_ + m0 + j * 4] = v;
        }
    }
}

// ---------------- K3: flash attention (round-7), swapped operands, split-KV ----------------
// grid = 4*128 = 512 blocks, 512 thr (8 waves). Each wave: same 16 queries, 256-key slice.
__global__ __launch_bounds__(512) void attn(const short* __restrict__ Q,
                                            const short* __restrict__ K,
                                            const short* __restrict__ Vt,
                                            float* __restrict__ out) {
    __shared__ float accw[8][16][68];
    __shared__ short P_lds[8][16][72];
    __shared__ float Mw[8][16];
    __shared__ float Lw[8][16];
    __shared__ float Ltot[16];

    int tid = threadIdx.x, wid = tid >> 6, lane = tid & 63;
    int l15 = lane & 15, lg = lane >> 4;
    int b_ = blockIdx.x >> 7;
    int q0 = (blockIdx.x & 127) * 16;
    const short* Kb = K + b_ * 2048 * 64;
    const short* Vb = Vt + b_ * 64 * 2048;

    const short* Qp = Q + (b_ * 2048 + q0 + l15) * 64 + lg * 8;
    bf16x8 bq0 = *(const bf16x8*)Qp;
    bf16x8 bq1 = *(const bf16x8*)(Qp + 32);

    f32x4 acc[4];
    #pragma unroll
    for (int t = 0; t < 4; ++t) acc[t] = (f32x4){0.f, 0.f, 0.f, 0.f};
    float m_run = -INFINITY, l_run = 0.f;

    int kv0 = wid * 256;
    for (int kv = kv0; kv < kv0 + 256; kv += 64) {
        f32x4 s[4];
        #pragma unroll
        for (int kt = 0; kt < 4; ++kt) {
            const short* Kp = Kb + (kv + kt * 16 + l15) * 64 + lg * 8;
            bf16x8 ak0 = *(const bf16x8*)Kp;
            bf16x8 ak1 = *(const bf16x8*)(Kp + 32);
            f32x4 z = (f32x4){0.f, 0.f, 0.f, 0.f};
            z = __builtin_amdgcn_mfma_f32_16x16x32_bf16(ak0, bq0, z, 0, 0, 0);
            s[kt] = __builtin_amdgcn_mfma_f32_16x16x32_bf16(ak1, bq1, z, 0, 0, 0);
        }

        float m01 = fmaxf(fmaxf(s[0][0], s[0][1]), fmaxf(s[0][2], s[0][3]));
        float m23 = fmaxf(fmaxf(s[1][0], s[1][1]), fmaxf(s[1][2], s[1][3]));
        float m45 = fmaxf(fmaxf(s[2][0], s[2][1]), fmaxf(s[2][2], s[2][3]));
        float m67 = fmaxf(fmaxf(s[3][0], s[3][1]), fmaxf(s[3][2], s[3][3]));
        float mt = fmaxf(fmaxf(m01, m23), fmaxf(m45, m67));
        mt = fmaxf(mt, __shfl_xor(mt, 16));
        mt = fmaxf(mt, __shfl_xor(mt, 32));
        float mn = fmaxf(m_run, mt);
        float c = exp2f(m_run - mn);
        m_run = mn;
        float rs = 0.f;
        #pragma unroll
        for (int kt = 0; kt < 4; ++kt)
            #pragma unroll
            for (int r = 0; r < 4; ++r) {
                float p = exp2f(s[kt][r] - mn);
                s[kt][r] = p;
                rs += p;
            }
        rs += __shfl_xor(rs, 16);
        rs += __shfl_xor(rs, 32);
        l_run = l_run * c + rs;
        #pragma unroll
        for (int t = 0; t < 4; ++t)
            #pragma unroll
            for (int r = 0; r < 4; ++r) acc[t][r] *= c;

        #pragma unroll
        for (int kt = 0; kt < 4; ++kt) {
            u16x4 h;
            h[0] = (unsigned short)f2bf(s[kt][0]);
            h[1] = (unsigned short)f2bf(s[kt][1]);
            h[2] = (unsigned short)f2bf(s[kt][2]);
            h[3] = (unsigned short)f2bf(s[kt][3]);
            *(u16x4*)&P_lds[wid][l15][kt * 16 + lg * 4] = h;
        }

        #pragma unroll
        for (int ps = 0; ps < 2; ++ps) {
            bf16x8 bp = *(const bf16x8*)&P_lds[wid][l15][ps * 32 + lg * 8];
            #pragma unroll
            for (int t = 0; t < 4; ++t) {
                const short* Vp = Vb + (t * 16 + l15) * 2048 + kv + ps * 32 + lg * 8;
                bf16x8 av = *(const bf16x8*)Vp;
                acc[t] = __builtin_amdgcn_mfma_f32_16x16x32_bf16(av, bp, acc[t], 0, 0, 0);
            }
        }
    }

    if (lg == 0) {
        Mw[wid][l15] = m_run;
        Lw[wid][l15] = l_run;
    }
    __syncthreads();

    float mtot = Mw[0][l15];
    #pragma unroll
    for (int w = 1; w < 8; ++w) mtot = fmaxf(mtot, Mw[w][l15]);
    float fac = exp2f(m_run - mtot);
    #pragma unroll
    for (int t = 0; t < 4; ++t) {
        f32x4 v = acc[t];
        v[0] *= fac; v[1] *= fac; v[2] *= fac; v[3] *= fac;
        *(f32x4*)&accw[wid][l15][t * 16 + lg * 4] = v;
    }

    if (wid == 0 && lg == 0) {
        float L = 0.f;
        #pragma unroll
        for (int w = 0; w < 8; ++w)
            L += Lw[w][l15] * exp2f(Mw[w][l15] - mtot);
        Ltot[l15] = L;
    }
    __syncthreads();

    #pragma unroll
    for (int j = 0; j < 2; ++j) {
        int o = tid + j * 512;
        int row = o >> 6, col = o & 63;
        float ssum = 0.f;
        #pragma unroll
        for (int w = 0; w < 8; ++w) ssum += accw[w][row][col];
        out[(b_ * 2048 + q0 + row) * 64 + col] = ssum / Ltot[row];
    }
}

extern "C" void kernel_launch(void* const* d_in, const int* in_sizes, int n_in,
                              void* d_out, int out_size, void* d_ws, size_t ws_size,
                              hipStream_t stream) {
    const float* x  = (const float*)d_in[0];
    const float* Wq = (const float*)d_in[1];
    const float* Wk = (const float*)d_in[2];
    const float* Wv = (const float*)d_in[3];
    float* out = (float*)d_out;

    char* ws = (char*)d_ws;
    short* Wt = (short*)ws;                              // 192*1024*2   = 393216 B
    short* Q  = (short*)(ws + 393216);                   // 8192*64*2    = 1048576 B
    short* K  = (short*)(ws + 393216 + 1048576);         // 1048576 B
    short* Vt = (short*)(ws + 393216 + 2 * 1048576);     // 1048576 B   (total ~3.4 MB)

    hipLaunchKernelGGL(wtrans,   dim3(48),  dim3(256), 0, stream, Wq, Wk, Wv, Wt);
    hipLaunchKernelGGL(qkv_proj, dim3(512), dim3(256), 0, stream, x, Wt, Q, K, Vt);
    hipLaunchKernelGGL(attn,     dim3(512), dim3(512), 0, stream, Q, K, Vt, out);
}

// Round 15
// 63.377 us; speedup vs baseline: 1.2476x; 1.0753x over previous
//
#include <hip/hip_runtime.h>
#include <hip/hip_bf16.h>

// Self-attention, fused QKV: x[4,2048,1024] f32, Wq/Wk/Wv[1024,64] f32 -> out[4,2048,64] f32
// bf16 MFMA (16x16x32), fp32 accumulation.
//   K1: W -> Wt bf16 [192][1024] via LDS tile-transpose (coalesced both sides)
//   K2: QKV projection via global_load_lds, 3-buffer counted-vmcnt pipeline (T4):
//       issue S(t+2) at step t, s_waitcnt vmcnt(5) + raw s_barrier -- loads stay in
//       flight across barriers instead of draining vmcnt(0) every step (m97 stall).
//   K3: flash attention (round-7) + s_setprio around MFMA clusters (T5, attn-positive).

typedef __attribute__((ext_vector_type(8))) short bf16x8;
typedef __attribute__((ext_vector_type(4))) float f32x4;
typedef __attribute__((ext_vector_type(4))) unsigned short u16x4;

#define QSCALE 0.1803368801111832f   // 0.125 * log2(e); makes logits exp2-domain

__device__ __forceinline__ short f2bf(float f) {
    union { float f; unsigned u; } v; v.f = f;
    unsigned r = v.u + 0x7FFF + ((v.u >> 16) & 1);   // round-to-nearest-even
    return (short)(r >> 16);
}

__device__ __forceinline__ void gload16(const void* src, void* dst) {
    __builtin_amdgcn_global_load_lds(
        (const __attribute__((address_space(1))) unsigned int*)src,
        (__attribute__((address_space(3))) unsigned int*)dst, 16, 0, 0);
}

// ---------------- K1: weight transpose + bf16 convert (coalesced) ----------------
__global__ __launch_bounds__(256) void wtrans(const float* __restrict__ Wq,
                                              const float* __restrict__ Wk,
                                              const float* __restrict__ Wv,
                                              short* __restrict__ Wt) {
    __shared__ short lds[64][66];
    int warr = blockIdx.x / 16;
    int d0 = (blockIdx.x % 16) * 64;
    const float* W = (warr == 0) ? Wq : (warr == 1) ? Wk : Wv;
    int rg = threadIdx.x >> 6;
    int c  = threadIdx.x & 63;
    #pragma unroll
    for (int p = 0; p < 16; ++p) {
        int d = p * 4 + rg;
        lds[d][c] = f2bf(W[(d0 + d) * 64 + c]);
    }
    __syncthreads();
    #pragma unroll
    for (int p = 0; p < 16; ++p) {
        int n = p * 4 + rg;
        Wt[(warr * 64 + n) * 1024 + d0 + c] = lds[c][n];
    }
}

// ---------------- K2: QKV projection, 3-buffer counted-vmcnt gload_lds GEMM ----------------
// grid = 256 M-tiles x 2 N-halves = 512 blocks, 256 thr (4 waves).
// Tile M=32 x N=96, BK=64 (16 K-steps). Per-step stage = 5 gload16/thread (20KB/block).
// Swizzle: linear LDS dest + inverse-swizzled global source + swizzled ds_read (rule #21).
__global__ __launch_bounds__(256) void qkv_proj(const float* __restrict__ x,
                                                const short* __restrict__ Wt,
                                                short* __restrict__ Q,
                                                short* __restrict__ K,
                                                short* __restrict__ Vt) {
    __shared__ char stage_lds[3][20480];
    __shared__ short Vlds[32][72];

    int tid = threadIdx.x;
    int wid = tid >> 6, lane = tid & 63;
    int l15 = lane & 15, lg = lane >> 4;
    int wr = wid >> 1, wn = wid & 1;
    int mbase = (blockIdx.x >> 1) * 32;
    int nbase = (blockIdx.x & 1) * 96;

    // staging source offsets (pre-swizzled); chunks 0..7 = A (4 rows x 256B),
    // 8..19 = B (8 rows x 128B)
    int a_soff[2];
    #pragma unroll
    for (int j = 0; j < 2; ++j) {
        int chunk = wid + j * 4;
        int row = chunk * 4 + (lane >> 4);
        int slot16 = lane & 15;
        int s32 = slot16 >> 1, h16 = slot16 & 1;
        int s32s = s32 ^ (row & 7);
        a_soff[j] = (mbase + row) * 1024 + s32s * 8 + h16 * 4;   // float offset
    }
    int b_soff[3];
    #pragma unroll
    for (int j = 0; j < 3; ++j) {
        int cb = wid + j * 4;
        int row = cb * 8 + (lane >> 3);
        int slot = lane & 7;
        int ss = slot ^ (row & 7);
        b_soff[j] = (nbase + row) * 1024 + ss * 8;               // short offset
    }

    f32x4 acc[3];
    #pragma unroll
    for (int f = 0; f < 3; ++f) acc[f] = (f32x4){0.f, 0.f, 0.f, 0.f};

    char* B0 = &stage_lds[0][0];
    char* B1 = &stage_lds[1][0];
    char* B2 = &stage_lds[2][0];

#define STAGE(step, base)                                                    \
    {                                                                        \
        int k0_ = (step) * 64;                                               \
        _Pragma("unroll")                                                    \
        for (int j = 0; j < 2; ++j)                                          \
            gload16(x + a_soff[j] + k0_, (base) + (wid + j * 4) * 1024);     \
        _Pragma("unroll")                                                    \
        for (int j = 0; j < 3; ++j)                                          \
            gload16(Wt + b_soff[j] + k0_, (base) + 8192 + (wid + j * 4) * 1024); \
    }

    // prologue: two tiles in flight, confirm the first
    STAGE(0, B0);
    STAGE(1, B1);
    asm volatile("s_waitcnt vmcnt(5)" ::: "memory");
    __builtin_amdgcn_s_barrier();
    __builtin_amdgcn_sched_barrier(0);

    for (int t = 0; t < 16; ++t) {
        int cm = t % 3;
        char* cbuf = (cm == 0) ? B0 : (cm == 1) ? B1 : B2;
        if (t + 2 < 16) {
            int nm = (t + 2) % 3;
            char* nbuf = (nm == 0) ? B0 : (nm == 1) ? B1 : B2;
            STAGE(t + 2, nbuf);
        }
        const char* Ab = cbuf;
        const char* Bb = cbuf + 8192;
        int arow = wr * 16 + l15;
        __builtin_amdgcn_s_setprio(1);
        #pragma unroll
        for (int h = 0; h < 2; ++h) {
            int s32s = (h * 4 + lg) ^ (arow & 7);
            const float4* ap = (const float4*)(Ab + arow * 256 + s32s * 32);
            float4 f0 = ap[0];
            float4 f1 = ap[1];
            bf16x8 a;
            a[0] = f2bf(f0.x); a[1] = f2bf(f0.y); a[2] = f2bf(f0.z); a[3] = f2bf(f0.w);
            a[4] = f2bf(f1.x); a[5] = f2bf(f1.y); a[6] = f2bf(f1.z); a[7] = f2bf(f1.w);
            #pragma unroll
            for (int f = 0; f < 3; ++f) {
                int brow = (wn * 3 + f) * 16 + l15;
                int ss = (h * 4 + lg) ^ (brow & 7);
                bf16x8 b = *(const bf16x8*)(Bb + brow * 128 + ss * 16);
                acc[f] = __builtin_amdgcn_mfma_f32_16x16x32_bf16(a, b, acc[f], 0, 0, 0);
            }
        }
        __builtin_amdgcn_s_setprio(0);
        if (t < 15) {
            if (t == 14) {
                asm volatile("s_waitcnt vmcnt(0)" ::: "memory");
            } else {
                asm volatile("s_waitcnt vmcnt(5)" ::: "memory");
            }
            __builtin_amdgcn_s_barrier();
            __builtin_amdgcn_sched_barrier(0);
        }
    }
#undef STAGE

    // epilogue. n = nbase + (wn*3+f)*16 + l15; m = mbase + wr*16 + lg*4 + r.
    #pragma unroll
    for (int f = 0; f < 3; ++f) {
        int n = nbase + (wn * 3 + f) * 16 + l15;
        #pragma unroll
        for (int r = 0; r < 4; ++r) {
            int ml = wr * 16 + lg * 4 + r;
            int m = mbase + ml;
            float v = acc[f][r];
            if (n < 64) {
                Q[m * 64 + n] = f2bf(v * QSCALE);
            } else if (n < 128) {
                K[m * 64 + (n - 64)] = f2bf(v);
            } else {
                Vlds[ml][n - 128] = f2bf(v);
            }
        }
    }
    if (nbase == 96) {    // block-uniform branch: barrier legal
        __syncthreads();
        int dk = tid >> 2;
        int m0 = (tid & 3) * 8;
        int b_ = mbase >> 11;
        int s_ = mbase & 2047;
        #pragma unroll
        for (int j = 0; j < 2; ++j) {
            u16x4 v;
            #pragma unroll
            for (int i = 0; i < 4; ++i) v[i] = (unsigned short)Vlds[m0 + j * 4 + i][dk];
            *(u16x4*)&Vt[(b_ * 64 + dk) * 2048 + s_ + m0 + j * 4] = v;
        }
    }
}

// ---------------- K3: flash attention (round-7 + setprio), swapped operands, split-KV ----------------
// grid = 4*128 = 512 blocks, 512 thr (8 waves). Each wave: same 16 queries, 256-key slice.
__global__ __launch_bounds__(512) void attn(const short* __restrict__ Q,
                                            const short* __restrict__ K,
                                            const short* __restrict__ Vt,
                                            float* __restrict__ out) {
    __shared__ float accw[8][16][68];
    __shared__ short P_lds[8][16][72];
    __shared__ float Mw[8][16];
    __shared__ float Lw[8][16];
    __shared__ float Ltot[16];

    int tid = threadIdx.x, wid = tid >> 6, lane = tid & 63;
    int l15 = lane & 15, lg = lane >> 4;
    int b_ = blockIdx.x >> 7;
    int q0 = (blockIdx.x & 127) * 16;
    const short* Kb = K + b_ * 2048 * 64;
    const short* Vb = Vt + b_ * 64 * 2048;

    const short* Qp = Q + (b_ * 2048 + q0 + l15) * 64 + lg * 8;
    bf16x8 bq0 = *(const bf16x8*)Qp;
    bf16x8 bq1 = *(const bf16x8*)(Qp + 32);

    f32x4 acc[4];
    #pragma unroll
    for (int t = 0; t < 4; ++t) acc[t] = (f32x4){0.f, 0.f, 0.f, 0.f};
    float m_run = -INFINITY, l_run = 0.f;

    int kv0 = wid * 256;
    for (int kv = kv0; kv < kv0 + 256; kv += 64) {
        f32x4 s[4];
        __builtin_amdgcn_s_setprio(1);
        #pragma unroll
        for (int kt = 0; kt < 4; ++kt) {
            const short* Kp = Kb + (kv + kt * 16 + l15) * 64 + lg * 8;
            bf16x8 ak0 = *(const bf16x8*)Kp;
            bf16x8 ak1 = *(const bf16x8*)(Kp + 32);
            f32x4 z = (f32x4){0.f, 0.f, 0.f, 0.f};
            z = __builtin_amdgcn_mfma_f32_16x16x32_bf16(ak0, bq0, z, 0, 0, 0);
            s[kt] = __builtin_amdgcn_mfma_f32_16x16x32_bf16(ak1, bq1, z, 0, 0, 0);
        }
        __builtin_amdgcn_s_setprio(0);

        float m01 = fmaxf(fmaxf(s[0][0], s[0][1]), fmaxf(s[0][2], s[0][3]));
        float m23 = fmaxf(fmaxf(s[1][0], s[1][1]), fmaxf(s[1][2], s[1][3]));
        float m45 = fmaxf(fmaxf(s[2][0], s[2][1]), fmaxf(s[2][2], s[2][3]));
        float m67 = fmaxf(fmaxf(s[3][0], s[3][1]), fmaxf(s[3][2], s[3][3]));
        float mt = fmaxf(fmaxf(m01, m23), fmaxf(m45, m67));
        mt = fmaxf(mt, __shfl_xor(mt, 16));
        mt = fmaxf(mt, __shfl_xor(mt, 32));
        float mn = fmaxf(m_run, mt);
        float c = exp2f(m_run - mn);
        m_run = mn;
        float rs = 0.f;
        #pragma unroll
        for (int kt = 0; kt < 4; ++kt)
            #pragma unroll
            for (int r = 0; r < 4; ++r) {
                float p = exp2f(s[kt][r] - mn);
                s[kt][r] = p;
                rs += p;
            }
        rs += __shfl_xor(rs, 16);
        rs += __shfl_xor(rs, 32);
        l_run = l_run * c + rs;
        #pragma unroll
        for (int t = 0; t < 4; ++t)
            #pragma unroll
            for (int r = 0; r < 4; ++r) acc[t][r] *= c;

        #pragma unroll
        for (int kt = 0; kt < 4; ++kt) {
            u16x4 h;
            h[0] = (unsigned short)f2bf(s[kt][0]);
            h[1] = (unsigned short)f2bf(s[kt][1]);
            h[2] = (unsigned short)f2bf(s[kt][2]);
            h[3] = (unsigned short)f2bf(s[kt][3]);
            *(u16x4*)&P_lds[wid][l15][kt * 16 + lg * 4] = h;
        }

        __builtin_amdgcn_s_setprio(1);
        #pragma unroll
        for (int ps = 0; ps < 2; ++ps) {
            bf16x8 bp = *(const bf16x8*)&P_lds[wid][l15][ps * 32 + lg * 8];
            #pragma unroll
            for (int t = 0; t < 4; ++t) {
                const short* Vp = Vb + (t * 16 + l15) * 2048 + kv + ps * 32 + lg * 8;
                bf16x8 av = *(const bf16x8*)Vp;
                acc[t] = __builtin_amdgcn_mfma_f32_16x16x32_bf16(av, bp, acc[t], 0, 0, 0);
            }
        }
        __builtin_amdgcn_s_setprio(0);
    }

    if (lg == 0) {
        Mw[wid][l15] = m_run;
        Lw[wid][l15] = l_run;
    }
    __syncthreads();

    float mtot = Mw[0][l15];
    #pragma unroll
    for (int w = 1; w < 8; ++w) mtot = fmaxf(mtot, Mw[w][l15]);
    float fac = exp2f(m_run - mtot);
    #pragma unroll
    for (int t = 0; t < 4; ++t) {
        f32x4 v = acc[t];
        v[0] *= fac; v[1] *= fac; v[2] *= fac; v[3] *= fac;
        *(f32x4*)&accw[wid][l15][t * 16 + lg * 4] = v;
    }

    if (wid == 0 && lg == 0) {
        float L = 0.f;
        #pragma unroll
        for (int w = 0; w < 8; ++w)
            L += Lw[w][l15] * exp2f(Mw[w][l15] - mtot);
        Ltot[l15] = L;
    }
    __syncthreads();

    #pragma unroll
    for (int j = 0; j < 2; ++j) {
        int o = tid + j * 512;
        int row = o >> 6, col = o & 63;
        float ssum = 0.f;
        #pragma unroll
        for (int w = 0; w < 8; ++w) ssum += accw[w][row][col];
        out[(b_ * 2048 + q0 + row) * 64 + col] = ssum / Ltot[row];
    }
}

extern "C" void kernel_launch(void* const* d_in, const int* in_sizes, int n_in,
                              void* d_out, int out_size, void* d_ws, size_t ws_size,
                              hipStream_t stream) {
    const float* x  = (const float*)d_in[0];
    const float* Wq = (const float*)d_in[1];
    const float* Wk = (const float*)d_in[2];
    const float* Wv = (const float*)d_in[3];
    float* out = (float*)d_out;

    char* ws = (char*)d_ws;
    short* Wt = (short*)ws;                              // 192*1024*2   = 393216 B
    short* Q  = (short*)(ws + 393216);                   // 8192*64*2    = 1048576 B
    short* K  = (short*)(ws + 393216 + 1048576);         // 1048576 B
    short* Vt = (short*)(ws + 393216 + 2 * 1048576);     // 1048576 B   (total ~3.4 MB)

    hipLaunchKernelGGL(wtrans,   dim3(48),  dim3(256), 0, stream, Wq, Wk, Wv, Wt);
    hipLaunchKernelGGL(qkv_proj, dim3(512), dim3(256), 0, stream, x, Wt, Q, K, Vt);
    hipLaunchKernelGGL(attn,     dim3(512), dim3(512), 0, stream, Q, K, Vt, out);
}

// Round 16
// 62.529 us; speedup vs baseline: 1.2645x; 1.0136x over previous
//
#include <hip/hip_runtime.h>
#include <hip/hip_bf16.h>

// Self-attention, fused QKV: x[4,2048,1024] f32, Wq/Wk/Wv[1024,64] f32 -> out[4,2048,64] f32
// bf16 MFMA (16x16x32), fp32 accumulation.
//   K1: wtrans  -- W -> Wt bf16 [192][1024], LDS tile-transpose.
//   K2: qkv_proj -- gload_lds 3-buffer counted-vmcnt pipeline (r15) + T1 XCD swizzle
//       (N-half pairs share the A-tile on the same XCD L2).
//   K3: attn16  -- flash attn, split-KV x16 (1024 blocks, 8 waves x 128 keys),
//       partials (m,l,scaled acc) to d_ws; T1 swizzle; setprio on MFMA clusters.
//   K4: attn_combine -- deterministic 2-way merge of the kv-halves.
//   Fallback: if ws_size < needed, run the proven r15 attn (split x8, direct out).

typedef __attribute__((ext_vector_type(8))) short bf16x8;
typedef __attribute__((ext_vector_type(4))) float f32x4;
typedef __attribute__((ext_vector_type(4))) unsigned short u16x4;

#define QSCALE 0.1803368801111832f   // 0.125 * log2(e); logits land in exp2 domain

__device__ __forceinline__ short f2bf(float f) {
    union { float f; unsigned u; } v; v.f = f;
    unsigned r = v.u + 0x7FFF + ((v.u >> 16) & 1);   // round-to-nearest-even
    return (short)(r >> 16);
}

__device__ __forceinline__ void gload16(const void* src, void* dst) {
    __builtin_amdgcn_global_load_lds(
        (const __attribute__((address_space(1))) unsigned int*)src,
        (__attribute__((address_space(3))) unsigned int*)dst, 16, 0, 0);
}

// ---------------- K1: weight transpose + bf16 convert (coalesced) ----------------
__global__ __launch_bounds__(256) void wtrans(const float* __restrict__ Wq,
                                              const float* __restrict__ Wk,
                                              const float* __restrict__ Wv,
                                              short* __restrict__ Wt) {
    __shared__ short lds[64][66];
    int warr = blockIdx.x / 16;
    int d0 = (blockIdx.x % 16) * 64;
    const float* W = (warr == 0) ? Wq : (warr == 1) ? Wk : Wv;
    int rg = threadIdx.x >> 6;
    int c  = threadIdx.x & 63;
    #pragma unroll
    for (int p = 0; p < 16; ++p) {
        int d = p * 4 + rg;
        lds[d][c] = f2bf(W[(d0 + d) * 64 + c]);
    }
    __syncthreads();
    #pragma unroll
    for (int p = 0; p < 16; ++p) {
        int n = p * 4 + rg;
        Wt[(warr * 64 + n) * 1024 + d0 + c] = lds[c][n];
    }
}

// ---------------- K2: QKV projection (r15 pipeline + T1 swizzle) ----------------
__global__ __launch_bounds__(256) void qkv_proj(const float* __restrict__ x,
                                                const short* __restrict__ Wt,
                                                short* __restrict__ Q,
                                                short* __restrict__ K,
                                                short* __restrict__ Vt) {
    __shared__ char stage_lds[3][20480];
    __shared__ short Vlds[32][72];

    int tid = threadIdx.x;
    int wid = tid >> 6, lane = tid & 63;
    int l15 = lane & 15, lg = lane >> 4;
    int wr = wid >> 1, wn = wid & 1;
    // T1 chunked swizzle (512 = 8 XCDs x 64): pairs (2i,2i+1) -> same XCD L2
    int logical = (blockIdx.x & 7) * 64 + (blockIdx.x >> 3);
    int mbase = (logical >> 1) * 32;
    int nbase = (logical & 1) * 96;

    int a_soff[2];
    #pragma unroll
    for (int j = 0; j < 2; ++j) {
        int chunk = wid + j * 4;
        int row = chunk * 4 + (lane >> 4);
        int slot16 = lane & 15;
        int s32 = slot16 >> 1, h16 = slot16 & 1;
        int s32s = s32 ^ (row & 7);
        a_soff[j] = (mbase + row) * 1024 + s32s * 8 + h16 * 4;   // float offset
    }
    int b_soff[3];
    #pragma unroll
    for (int j = 0; j < 3; ++j) {
        int cb = wid + j * 4;
        int row = cb * 8 + (lane >> 3);
        int slot = lane & 7;
        int ss = slot ^ (row & 7);
        b_soff[j] = (nbase + row) * 1024 + ss * 8;               // short offset
    }

    f32x4 acc[3];
    #pragma unroll
    for (int f = 0; f < 3; ++f) acc[f] = (f32x4){0.f, 0.f, 0.f, 0.f};

    char* B0 = &stage_lds[0][0];
    char* B1 = &stage_lds[1][0];
    char* B2 = &stage_lds[2][0];

#define STAGE(step, base)                                                    \
    {                                                                        \
        int k0_ = (step) * 64;                                               \
        _Pragma("unroll")                                                    \
        for (int j = 0; j < 2; ++j)                                          \
            gload16(x + a_soff[j] + k0_, (base) + (wid + j * 4) * 1024);     \
        _Pragma("unroll")                                                    \
        for (int j = 0; j < 3; ++j)                                          \
            gload16(Wt + b_soff[j] + k0_, (base) + 8192 + (wid + j * 4) * 1024); \
    }

    STAGE(0, B0);
    STAGE(1, B1);
    asm volatile("s_waitcnt vmcnt(5)" ::: "memory");
    __builtin_amdgcn_s_barrier();
    __builtin_amdgcn_sched_barrier(0);

    for (int t = 0; t < 16; ++t) {
        int cm = t % 3;
        char* cbuf = (cm == 0) ? B0 : (cm == 1) ? B1 : B2;
        if (t + 2 < 16) {
            int nm = (t + 2) % 3;
            char* nbuf = (nm == 0) ? B0 : (nm == 1) ? B1 : B2;
            STAGE(t + 2, nbuf);
        }
        const char* Ab = cbuf;
        const char* Bb = cbuf + 8192;
        int arow = wr * 16 + l15;
        __builtin_amdgcn_s_setprio(1);
        #pragma unroll
        for (int h = 0; h < 2; ++h) {
            int s32s = (h * 4 + lg) ^ (arow & 7);
            const float4* ap = (const float4*)(Ab + arow * 256 + s32s * 32);
            float4 f0 = ap[0];
            float4 f1 = ap[1];
            bf16x8 a;
            a[0] = f2bf(f0.x); a[1] = f2bf(f0.y); a[2] = f2bf(f0.z); a[3] = f2bf(f0.w);
            a[4] = f2bf(f1.x); a[5] = f2bf(f1.y); a[6] = f2bf(f1.z); a[7] = f2bf(f1.w);
            #pragma unroll
            for (int f = 0; f < 3; ++f) {
                int brow = (wn * 3 + f) * 16 + l15;
                int ss = (h * 4 + lg) ^ (brow & 7);
                bf16x8 b = *(const bf16x8*)(Bb + brow * 128 + ss * 16);
                acc[f] = __builtin_amdgcn_mfma_f32_16x16x32_bf16(a, b, acc[f], 0, 0, 0);
            }
        }
        __builtin_amdgcn_s_setprio(0);
        if (t < 15) {
            if (t == 14) {
                asm volatile("s_waitcnt vmcnt(0)" ::: "memory");
            } else {
                asm volatile("s_waitcnt vmcnt(5)" ::: "memory");
            }
            __builtin_amdgcn_s_barrier();
            __builtin_amdgcn_sched_barrier(0);
        }
    }
#undef STAGE

    #pragma unroll
    for (int f = 0; f < 3; ++f) {
        int n = nbase + (wn * 3 + f) * 16 + l15;
        #pragma unroll
        for (int r = 0; r < 4; ++r) {
            int ml = wr * 16 + lg * 4 + r;
            int m = mbase + ml;
            float v = acc[f][r];
            if (n < 64) {
                Q[m * 64 + n] = f2bf(v * QSCALE);
            } else if (n < 128) {
                K[m * 64 + (n - 64)] = f2bf(v);
            } else {
                Vlds[ml][n - 128] = f2bf(v);
            }
        }
    }
    if (nbase == 96) {
        __syncthreads();
        int dk = tid >> 2;
        int m0 = (tid & 3) * 8;
        int b_ = mbase >> 11;
        int s_ = mbase & 2047;
        #pragma unroll
        for (int j = 0; j < 2; ++j) {
            u16x4 v;
            #pragma unroll
            for (int i = 0; i < 4; ++i) v[i] = (unsigned short)Vlds[m0 + j * 4 + i][dk];
            *(u16x4*)&Vt[(b_ * 64 + dk) * 2048 + s_ + m0 + j * 4] = v;
        }
    }
}

// ---------------- K3a: flash attention, split-KV x16, partials to ws ----------------
// grid = 1024 (b x qt x kvhalf), 512 thr. Wave: 16 queries x 128 keys.
__global__ __launch_bounds__(512) void attn16(const short* __restrict__ Q,
                                              const short* __restrict__ K,
                                              const short* __restrict__ Vt,
                                              float* __restrict__ P_m,
                                              float* __restrict__ P_l,
                                              float* __restrict__ P_acc) {
    __shared__ float accw[8][16][68];
    __shared__ short P_lds[8][16][72];
    __shared__ float Mw[8][16];
    __shared__ float Lw[8][16];
    __shared__ float Ltot[16];
    __shared__ float Mtot_s[16];

    int tid = threadIdx.x, wid = tid >> 6, lane = tid & 63;
    int l15 = lane & 15, lg = lane >> 4;
    // T1 chunked swizzle (1024 = 8 x 128); logical: b(2) | qt(7) | half(1)
    int logical = (blockIdx.x & 7) * 128 + (blockIdx.x >> 3);
    int b_ = logical >> 8;
    int qt = (logical >> 1) & 127;
    int half = logical & 1;
    int q0 = qt * 16;
    const short* Kb = K + b_ * 2048 * 64;
    const short* Vb = Vt + b_ * 64 * 2048;

    const short* Qp = Q + (b_ * 2048 + q0 + l15) * 64 + lg * 8;
    bf16x8 bq0 = *(const bf16x8*)Qp;
    bf16x8 bq1 = *(const bf16x8*)(Qp + 32);

    f32x4 acc[4];
    #pragma unroll
    for (int t = 0; t < 4; ++t) acc[t] = (f32x4){0.f, 0.f, 0.f, 0.f};
    float m_run = -INFINITY, l_run = 0.f;

    int kv0 = half * 1024 + wid * 128;
    for (int kv = kv0; kv < kv0 + 128; kv += 64) {
        f32x4 s[4];
        __builtin_amdgcn_s_setprio(1);
        #pragma unroll
        for (int kt = 0; kt < 4; ++kt) {
            const short* Kp = Kb + (kv + kt * 16 + l15) * 64 + lg * 8;
            bf16x8 ak0 = *(const bf16x8*)Kp;
            bf16x8 ak1 = *(const bf16x8*)(Kp + 32);
            f32x4 z = (f32x4){0.f, 0.f, 0.f, 0.f};
            z = __builtin_amdgcn_mfma_f32_16x16x32_bf16(ak0, bq0, z, 0, 0, 0);
            s[kt] = __builtin_amdgcn_mfma_f32_16x16x32_bf16(ak1, bq1, z, 0, 0, 0);
        }
        __builtin_amdgcn_s_setprio(0);

        float m01 = fmaxf(fmaxf(s[0][0], s[0][1]), fmaxf(s[0][2], s[0][3]));
        float m23 = fmaxf(fmaxf(s[1][0], s[1][1]), fmaxf(s[1][2], s[1][3]));
        float m45 = fmaxf(fmaxf(s[2][0], s[2][1]), fmaxf(s[2][2], s[2][3]));
        float m67 = fmaxf(fmaxf(s[3][0], s[3][1]), fmaxf(s[3][2], s[3][3]));
        float mt = fmaxf(fmaxf(m01, m23), fmaxf(m45, m67));
        mt = fmaxf(mt, __shfl_xor(mt, 16));
        mt = fmaxf(mt, __shfl_xor(mt, 32));
        float mn = fmaxf(m_run, mt);
        float c = exp2f(m_run - mn);
        m_run = mn;
        float rs = 0.f;
        #pragma unroll
        for (int kt = 0; kt < 4; ++kt)
            #pragma unroll
            for (int r = 0; r < 4; ++r) {
                float p = exp2f(s[kt][r] - mn);
                s[kt][r] = p;
                rs += p;
            }
        rs += __shfl_xor(rs, 16);
        rs += __shfl_xor(rs, 32);
        l_run = l_run * c + rs;
        #pragma unroll
        for (int t = 0; t < 4; ++t)
            #pragma unroll
            for (int r = 0; r < 4; ++r) acc[t][r] *= c;

        #pragma unroll
        for (int kt = 0; kt < 4; ++kt) {
            u16x4 h;
            h[0] = (unsigned short)f2bf(s[kt][0]);
            h[1] = (unsigned short)f2bf(s[kt][1]);
            h[2] = (unsigned short)f2bf(s[kt][2]);
            h[3] = (unsigned short)f2bf(s[kt][3]);
            *(u16x4*)&P_lds[wid][l15][kt * 16 + lg * 4] = h;
        }

        __builtin_amdgcn_s_setprio(1);
        #pragma unroll
        for (int ps = 0; ps < 2; ++ps) {
            bf16x8 bp = *(const bf16x8*)&P_lds[wid][l15][ps * 32 + lg * 8];
            #pragma unroll
            for (int t = 0; t < 4; ++t) {
                const short* Vp = Vb + (t * 16 + l15) * 2048 + kv + ps * 32 + lg * 8;
                bf16x8 av = *(const bf16x8*)Vp;
                acc[t] = __builtin_amdgcn_mfma_f32_16x16x32_bf16(av, bp, acc[t], 0, 0, 0);
            }
        }
        __builtin_amdgcn_s_setprio(0);
    }

    // in-block combine over 8 waves -> one partial per block
    if (lg == 0) {
        Mw[wid][l15] = m_run;
        Lw[wid][l15] = l_run;
    }
    __syncthreads();

    float mtot = Mw[0][l15];
    #pragma unroll
    for (int w = 1; w < 8; ++w) mtot = fmaxf(mtot, Mw[w][l15]);
    float fac = exp2f(m_run - mtot);
    #pragma unroll
    for (int t = 0; t < 4; ++t) {
        f32x4 v = acc[t];
        v[0] *= fac; v[1] *= fac; v[2] *= fac; v[3] *= fac;
        *(f32x4*)&accw[wid][l15][t * 16 + lg * 4] = v;
    }

    if (wid == 0 && lg == 0) {
        float L = 0.f;
        #pragma unroll
        for (int w = 0; w < 8; ++w)
            L += Lw[w][l15] * exp2f(Mw[w][l15] - mtot);
        Ltot[l15] = L;
        Mtot_s[l15] = mtot;
    }
    __syncthreads();

    int pidx = logical;   // 0..1023
    #pragma unroll
    for (int j = 0; j < 2; ++j) {
        int o = tid + j * 512;
        int row = o >> 6, col = o & 63;
        float ssum = 0.f;
        #pragma unroll
        for (int w = 0; w < 8; ++w) ssum += accw[w][row][col];
        P_acc[(pidx * 16 + row) * 64 + col] = ssum;
    }
    if (tid < 16) {
        P_m[pidx * 16 + tid] = Mtot_s[tid];
        P_l[pidx * 16 + tid] = Ltot[tid];
    }
}

// ---------------- K4: combine the two kv-halves ----------------
__global__ __launch_bounds__(256) void attn_combine(const float* __restrict__ P_m,
                                                    const float* __restrict__ P_l,
                                                    const float* __restrict__ P_acc,
                                                    float* __restrict__ out) {
    int pair = blockIdx.x;          // 0..511: b = pair>>7, qt = pair&127
    int b_ = pair >> 7, qt = pair & 127;
    int p0 = pair * 2, p1 = pair * 2 + 1;
    #pragma unroll
    for (int j = 0; j < 4; ++j) {
        int o = threadIdx.x + j * 256;
        int row = o >> 6, col = o & 63;
        float m0 = P_m[p0 * 16 + row], m1 = P_m[p1 * 16 + row];
        float l0 = P_l[p0 * 16 + row], l1 = P_l[p1 * 16 + row];
        float m = fmaxf(m0, m1);
        float f0 = exp2f(m0 - m), f1 = exp2f(m1 - m);
        float L = l0 * f0 + l1 * f1;
        float a = P_acc[(p0 * 16 + row) * 64 + col] * f0
                + P_acc[(p1 * 16 + row) * 64 + col] * f1;
        out[(b_ * 2048 + qt * 16 + row) * 64 + col] = a / L;
    }
}

// ---------------- K3b: fallback attn (r15, split x8, direct out) ----------------
__global__ __launch_bounds__(512) void attn(const short* __restrict__ Q,
                                            const short* __restrict__ K,
                                            const short* __restrict__ Vt,
                                            float* __restrict__ out) {
    __shared__ float accw[8][16][68];
    __shared__ short P_lds[8][16][72];
    __shared__ float Mw[8][16];
    __shared__ float Lw[8][16];
    __shared__ float Ltot[16];

    int tid = threadIdx.x, wid = tid >> 6, lane = tid & 63;
    int l15 = lane & 15, lg = lane >> 4;
    int logical = (blockIdx.x & 7) * 64 + (blockIdx.x >> 3);
    int b_ = logical >> 7;
    int q0 = (logical & 127) * 16;
    const short* Kb = K + b_ * 2048 * 64;
    const short* Vb = Vt + b_ * 64 * 2048;

    const short* Qp = Q + (b_ * 2048 + q0 + l15) * 64 + lg * 8;
    bf16x8 bq0 = *(const bf16x8*)Qp;
    bf16x8 bq1 = *(const bf16x8*)(Qp + 32);

    f32x4 acc[4];
    #pragma unroll
    for (int t = 0; t < 4; ++t) acc[t] = (f32x4){0.f, 0.f, 0.f, 0.f};
    float m_run = -INFINITY, l_run = 0.f;

    int kv0 = wid * 256;
    for (int kv = kv0; kv < kv0 + 256; kv += 64) {
        f32x4 s[4];
        __builtin_amdgcn_s_setprio(1);
        #pragma unroll
        for (int kt = 0; kt < 4; ++kt) {
            const short* Kp = Kb + (kv + kt * 16 + l15) * 64 + lg * 8;
            bf16x8 ak0 = *(const bf16x8*)Kp;
            bf16x8 ak1 = *(const bf16x8*)(Kp + 32);
            f32x4 z = (f32x4){0.f, 0.f, 0.f, 0.f};
            z = __builtin_amdgcn_mfma_f32_16x16x32_bf16(ak0, bq0, z, 0, 0, 0);
            s[kt] = __builtin_amdgcn_mfma_f32_16x16x32_bf16(ak1, bq1, z, 0, 0, 0);
        }
        __builtin_amdgcn_s_setprio(0);

        float m01 = fmaxf(fmaxf(s[0][0], s[0][1]), fmaxf(s[0][2], s[0][3]));
        float m23 = fmaxf(fmaxf(s[1][0], s[1][1]), fmaxf(s[1][2], s[1][3]));
        float m45 = fmaxf(fmaxf(s[2][0], s[2][1]), fmaxf(s[2][2], s[2][3]));
        float m67 = fmaxf(fmaxf(s[3][0], s[3][1]), fmaxf(s[3][2], s[3][3]));
        float mt = fmaxf(fmaxf(m01, m23), fmaxf(m45, m67));
        mt = fmaxf(mt, __shfl_xor(mt, 16));
        mt = fmaxf(mt, __shfl_xor(mt, 32));
        float mn = fmaxf(m_run, mt);
        float c = exp2f(m_run - mn);
        m_run = mn;
        float rs = 0.f;
        #pragma unroll
        for (int kt = 0; kt < 4; ++kt)
            #pragma unroll
            for (int r = 0; r < 4; ++r) {
                float p = exp2f(s[kt][r] - mn);
                s[kt][r] = p;
                rs += p;
            }
        rs += __shfl_xor(rs, 16);
        rs += __shfl_xor(rs, 32);
        l_run = l_run * c + rs;
        #pragma unroll
        for (int t = 0; t < 4; ++t)
            #pragma unroll
            for (int r = 0; r < 4; ++r) acc[t][r] *= c;

        #pragma unroll
        for (int kt = 0; kt < 4; ++kt) {
            u16x4 h;
            h[0] = (unsigned short)f2bf(s[kt][0]);
            h[1] = (unsigned short)f2bf(s[kt][1]);
            h[2] = (unsigned short)f2bf(s[kt][2]);
            h[3] = (unsigned short)f2bf(s[kt][3]);
            *(u16x4*)&P_lds[wid][l15][kt * 16 + lg * 4] = h;
        }

        __builtin_amdgcn_s_setprio(1);
        #pragma unroll
        for (int ps = 0; ps < 2; ++ps) {
            bf16x8 bp = *(const bf16x8*)&P_lds[wid][l15][ps * 32 + lg * 8];
            #pragma unroll
            for (int t = 0; t < 4; ++t) {
                const short* Vp = Vb + (t * 16 + l15) * 2048 + kv + ps * 32 + lg * 8;
                bf16x8 av = *(const bf16x8*)Vp;
                acc[t] = __builtin_amdgcn_mfma_f32_16x16x32_bf16(av, bp, acc[t], 0, 0, 0);
            }
        }
        __builtin_amdgcn_s_setprio(0);
    }

    if (lg == 0) {
        Mw[wid][l15] = m_run;
        Lw[wid][l15] = l_run;
    }
    __syncthreads();

    float mtot = Mw[0][l15];
    #pragma unroll
    for (int w = 1; w < 8; ++w) mtot = fmaxf(mtot, Mw[w][l15]);
    float fac = exp2f(m_run - mtot);
    #pragma unroll
    for (int t = 0; t < 4; ++t) {
        f32x4 v = acc[t];
        v[0] *= fac; v[1] *= fac; v[2] *= fac; v[3] *= fac;
        *(f32x4*)&accw[wid][l15][t * 16 + lg * 4] = v;
    }

    if (wid == 0 && lg == 0) {
        float L = 0.f;
        #pragma unroll
        for (int w = 0; w < 8; ++w)
            L += Lw[w][l15] * exp2f(Mw[w][l15] - mtot);
        Ltot[l15] = L;
    }
    __syncthreads();

    #pragma unroll
    for (int j = 0; j < 2; ++j) {
        int o = tid + j * 512;
        int row = o >> 6, col = o & 63;
        float ssum = 0.f;
        #pragma unroll
        for (int w = 0; w < 8; ++w) ssum += accw[w][row][col];
        out[(b_ * 2048 + q0 + row) * 64 + col] = ssum / Ltot[row];
    }
}

extern "C" void kernel_launch(void* const* d_in, const int* in_sizes, int n_in,
                              void* d_out, int out_size, void* d_ws, size_t ws_size,
                              hipStream_t stream) {
    const float* x  = (const float*)d_in[0];
    const float* Wq = (const float*)d_in[1];
    const float* Wk = (const float*)d_in[2];
    const float* Wv = (const float*)d_in[3];
    float* out = (float*)d_out;

    char* ws = (char*)d_ws;
    short* Wt = (short*)ws;                              // 393216 B
    short* Q  = (short*)(ws + 393216);                   // 1048576 B
    short* K  = (short*)(ws + 393216 + 1048576);         // 1048576 B
    short* Vt = (short*)(ws + 393216 + 2 * 1048576);     // 1048576 B  (3538944 total)
    float* P_m   = (float*)(ws + 3538944);               // 1024*16*4      = 65536 B
    float* P_l   = (float*)(ws + 3538944 + 65536);       // 65536 B
    float* P_acc = (float*)(ws + 3538944 + 131072);      // 1024*16*64*4   = 4194304 B
    const size_t WS_NEEDED = 3538944 + 131072 + 4194304; // 7864320

    hipLaunchKernelGGL(wtrans,   dim3(48),  dim3(256), 0, stream, Wq, Wk, Wv, Wt);
    hipLaunchKernelGGL(qkv_proj, dim3(512), dim3(256), 0, stream, x, Wt, Q, K, Vt);
    if (ws_size >= WS_NEEDED) {
        hipLaunchKernelGGL(attn16,       dim3(1024), dim3(512), 0, stream, Q, K, Vt, P_m, P_l, P_acc);
        hipLaunchKernelGGL(attn_combine, dim3(512),  dim3(256), 0, stream, P_m, P_l, P_acc, out);
    } else {
        hipLaunchKernelGGL(attn, dim3(512), dim3(512), 0, stream, Q, K, Vt, out);
    }
}